// Round 9
// baseline (295.181 us; speedup 1.0000x reference)
//
#include <hip/hip_runtime.h>
#include <hip/hip_bf16.h>
#include <stdint.h>

#define D_H 128

typedef __bf16 bf16_t;
typedef unsigned short u16;
typedef bf16_t bf16x8 __attribute__((ext_vector_type(8)));
typedef bf16_t bf16x4 __attribute__((ext_vector_type(4)));
typedef float  f32x4  __attribute__((ext_vector_type(4)));

// ---------------- degree count + rank capture + weight prep (fused) --------
__global__ void k_countrank(const int* __restrict__ dst, int* __restrict__ cnt,
                            u16* __restrict__ rank, int E, int crBlocks,
                            const float* __restrict__ W1, bf16_t* __restrict__ W1h,
                            bf16_t* __restrict__ W1l, int K1,
                            const float* __restrict__ W2, bf16_t* __restrict__ W2h,
                            bf16_t* __restrict__ W2l, int K2) {
    if ((int)blockIdx.x < crBlocks) {
        int e = blockIdx.x * 256 + threadIdx.x;
        if (e < E) rank[e] = (u16)atomicAdd(&cnt[dst[e]], 1);
        return;
    }
    int id = ((int)blockIdx.x - crBlocks) * 256 + threadIdx.x;
    int n1 = K1 * 128;
    if (id < n1) {
        int k = id >> 7, n = id & 127;
        float w = W1[id];
        bf16_t h = (bf16_t)w;
        W1h[(size_t)n * K1 + k] = h;
        W1l[(size_t)n * K1 + k] = (bf16_t)(w - (float)h);
    } else if (id < n1 + K2 * 128) {
        int id2 = id - n1;
        int k = id2 >> 7, n = id2 & 127;
        float w = W2[id2];
        bf16_t h = (bf16_t)w;
        W2h[(size_t)n * K2 + k] = h;
        W2l[(size_t)n * K2 + k] = (bf16_t)(w - (float)h);
    }
}

// ---------------- exclusive scan (3 kernels); scan1 also emits dis ----------
__global__ __launch_bounds__(1024) void k_scan1(const int* __restrict__ cnt,
                                                int* __restrict__ out,
                                                int* __restrict__ bsums,
                                                float* __restrict__ dis, int N) {
    __shared__ int tmp[1024];
    int t = threadIdx.x;
    int i = blockIdx.x * 1024 + t;
    int v = (i < N) ? cnt[i] : 0;
    if (i < N) dis[i] = 1.0f / sqrtf((float)(v + 1));
    tmp[t] = v;
    __syncthreads();
    for (int d = 1; d < 1024; d <<= 1) {
        int x = (t >= d) ? tmp[t - d] : 0;
        __syncthreads();
        tmp[t] += x;
        __syncthreads();
    }
    if (i < N) out[i] = tmp[t] - v;
    if (t == 1023) bsums[blockIdx.x] = tmp[t];
}

__global__ void k_scan2(int* __restrict__ bsums, int nb) {
    __shared__ int tmp[64];
    int t = threadIdx.x;
    int v = (t < nb) ? bsums[t] : 0;
    tmp[t] = v;
    __syncthreads();
    for (int d = 1; d < 64; d <<= 1) {
        int x = (t >= d) ? tmp[t - d] : 0;
        __syncthreads();
        tmp[t] += x;
        __syncthreads();
    }
    if (t < nb) bsums[t] = tmp[t] - v;
}

__global__ __launch_bounds__(1024) void k_scan3(int* __restrict__ off,
                                                const int* __restrict__ bsums,
                                                int N, int E) {
    int i = blockIdx.x * 1024 + threadIdx.x;
    if (i < N) off[i] += bsums[blockIdx.x];
    if (i == 0) off[N] = E;
}

// ---------------- LDS-free MFMA GEMMs ----------------
// BM=64, BN=64 per 256-thread block; each wave computes 32x32 (2x2 MFMA tiles).
// All A/B fragments loaded DIRECTLY from global (per-row 128B segments, B is
// L2-resident, A shared via L1 across same-row waves). No __syncthreads, no
// LDS, no lockstep: depth-1 register pipeline + ~20 waves/CU hide latency.
// blockIdx decode: row0 = (bx>>1)*64, col0 = (bx&1)*64.
#define FILL_PER 2

// layer-1 (fp32 A, hi/lo split in registers) + distributed CSR fill
__global__ __launch_bounds__(256) void k_mm1fill(
        const float* __restrict__ Af,
        const bf16_t* __restrict__ Wh, const bf16_t* __restrict__ Wl,
        const float* __restrict__ dis, bf16_t* __restrict__ Cb,
        int N, int K,
        const int* __restrict__ src, const int* __restrict__ dst,
        const int* __restrict__ off, const u16* __restrict__ rank,
        u16* __restrict__ csr16, int E, int totThreads) {
    const int t    = threadIdx.x;
    const int lane = t & 63;
    const int wave = t >> 6;            // 0..3
    const int row0 = ((int)blockIdx.x >> 1) * 64;
    const int col0 = ((int)blockIdx.x & 1) * 64;
    const int wm   = (wave & 1) * 32;
    const int wn   = (wave >> 1) * 32;
    const int fm   = lane & 15;
    const int fq   = lane >> 4;

    // ---- fill prologue: resolve scatter addresses ----
    const int g = (int)blockIdx.x * 256 + t;
    int epos[FILL_PER];
    u16 esrc[FILL_PER];
#pragma unroll
    for (int i = 0; i < FILL_PER; i++) {
        int e = g + i * totThreads;
        if (e < E) {
            int d = dst[e];
            epos[i] = off[d] + (int)rank[e];
            esrc[i] = (u16)src[e];
        } else {
            epos[i] = -1;
            esrc[i] = 0;
        }
    }

    // row/col base pointers (clamped rows: garbage rows never stored)
    int ra0 = row0 + wm + fm;      if (ra0 >= N) ra0 = N - 1;
    int ra1 = row0 + wm + 16 + fm; if (ra1 >= N) ra1 = N - 1;
    const float*  pa0 = Af + (size_t)ra0 * K + fq * 8;
    const float*  pa1 = Af + (size_t)ra1 * K + fq * 8;
    const bf16_t* pb0h = Wh + (size_t)(col0 + wn + fm) * K + fq * 8;
    const bf16_t* pb1h = Wh + (size_t)(col0 + wn + 16 + fm) * K + fq * 8;
    const bf16_t* pb0l = Wl + (size_t)(col0 + wn + fm) * K + fq * 8;
    const bf16_t* pb1l = Wl + (size_t)(col0 + wn + 16 + fm) * K + fq * 8;

    f32x4 acc[2][2] = {};

    float4 aA[2][2], aB[2][2];
    bf16x8 bhA[2], blA[2], bhB[2], blB[2];

#define LOAD1(kt, a, bh, bl) do {                                   \
        int kk = (kt) * 32;                                         \
        a[0][0] = *(const float4*)(pa0 + kk);                       \
        a[0][1] = *(const float4*)(pa0 + kk + 4);                   \
        a[1][0] = *(const float4*)(pa1 + kk);                       \
        a[1][1] = *(const float4*)(pa1 + kk + 4);                   \
        bh[0] = *(const bf16x8*)(pb0h + kk);                        \
        bh[1] = *(const bf16x8*)(pb1h + kk);                        \
        bl[0] = *(const bf16x8*)(pb0l + kk);                        \
        bl[1] = *(const bf16x8*)(pb1l + kk);                        \
    } while (0)

#define COMP1(a, bh, bl) do {                                       \
        bf16x8 ah[2], al[2];                                        \
        _Pragma("unroll")                                           \
        for (int mi = 0; mi < 2; mi++) {                            \
            float v0 = a[mi][0].x, v1 = a[mi][0].y, v2 = a[mi][0].z, v3 = a[mi][0].w; \
            float v4 = a[mi][1].x, v5 = a[mi][1].y, v6 = a[mi][1].z, v7 = a[mi][1].w; \
            bf16_t h0=(bf16_t)v0,h1=(bf16_t)v1,h2=(bf16_t)v2,h3=(bf16_t)v3;          \
            bf16_t h4=(bf16_t)v4,h5=(bf16_t)v5,h6=(bf16_t)v6,h7=(bf16_t)v7;          \
            ah[mi] = (bf16x8){h0,h1,h2,h3,h4,h5,h6,h7};             \
            al[mi] = (bf16x8){(bf16_t)(v0-(float)h0),(bf16_t)(v1-(float)h1),         \
                              (bf16_t)(v2-(float)h2),(bf16_t)(v3-(float)h3),         \
                              (bf16_t)(v4-(float)h4),(bf16_t)(v5-(float)h5),         \
                              (bf16_t)(v6-(float)h6),(bf16_t)(v7-(float)h7)};        \
        }                                                           \
        _Pragma("unroll")                                           \
        for (int mi = 0; mi < 2; mi++)                              \
            _Pragma("unroll")                                       \
            for (int ni = 0; ni < 2; ni++) {                        \
                acc[mi][ni] = __builtin_amdgcn_mfma_f32_16x16x32_bf16(ah[mi], bh[ni], acc[mi][ni], 0, 0, 0); \
                acc[mi][ni] = __builtin_amdgcn_mfma_f32_16x16x32_bf16(ah[mi], bl[ni], acc[mi][ni], 0, 0, 0); \
                acc[mi][ni] = __builtin_amdgcn_mfma_f32_16x16x32_bf16(al[mi], bh[ni], acc[mi][ni], 0, 0, 0); \
            }                                                       \
    } while (0)

    const int KT = K >> 5;              // 8
    LOAD1(0, aA, bhA, blA);
#pragma unroll
    for (int kt = 0; kt < 8; kt += 2) {
        LOAD1(kt + 1, aB, bhB, blB);
        COMP1(aA, bhA, blA);
        if (kt + 2 < KT) LOAD1(kt + 2, aA, bhA, blA);
        COMP1(aB, bhB, blB);
    }
#undef LOAD1
#undef COMP1

    // epilogue: C/D layout col=fm, row=fq*4+reg; scale by dis[row], store bf16
#pragma unroll
    for (int mi = 0; mi < 2; mi++)
#pragma unroll
        for (int r = 0; r < 4; r++) {
            int grow = row0 + wm + mi * 16 + fq * 4 + r;
            if (grow < N) {
                float dr = dis[grow];
#pragma unroll
                for (int ni = 0; ni < 2; ni++)
                    Cb[(size_t)grow * D_H + col0 + wn + ni * 16 + fm] = (bf16_t)(dr * acc[mi][ni][r]);
            }
        }

    // ---- fill epilogue: scattered 2B stores, fire and forget ----
#pragma unroll
    for (int i = 0; i < FILL_PER; i++)
        if (epos[i] >= 0) csr16[epos[i]] = esrc[i];
}

// layer-2 (bf16 hi/lo A), LDS-free, K=128
__global__ __launch_bounds__(256) void k_mm2(const bf16_t* __restrict__ Ah,
                                             const bf16_t* __restrict__ Al,
                                             const bf16_t* __restrict__ Wh,
                                             const bf16_t* __restrict__ Wl,
                                             const float* __restrict__ dis,
                                             bf16_t* __restrict__ Cb,
                                             int N, int K) {
    const int t    = threadIdx.x;
    const int lane = t & 63;
    const int wave = t >> 6;
    const int row0 = ((int)blockIdx.x >> 1) * 64;
    const int col0 = ((int)blockIdx.x & 1) * 64;
    const int wm   = (wave & 1) * 32;
    const int wn   = (wave >> 1) * 32;
    const int fm   = lane & 15;
    const int fq   = lane >> 4;

    int ra0 = row0 + wm + fm;      if (ra0 >= N) ra0 = N - 1;
    int ra1 = row0 + wm + 16 + fm; if (ra1 >= N) ra1 = N - 1;
    const bf16_t* pa0h = Ah + (size_t)ra0 * K + fq * 8;
    const bf16_t* pa1h = Ah + (size_t)ra1 * K + fq * 8;
    const bf16_t* pa0l = Al + (size_t)ra0 * K + fq * 8;
    const bf16_t* pa1l = Al + (size_t)ra1 * K + fq * 8;
    const bf16_t* pb0h = Wh + (size_t)(col0 + wn + fm) * K + fq * 8;
    const bf16_t* pb1h = Wh + (size_t)(col0 + wn + 16 + fm) * K + fq * 8;
    const bf16_t* pb0l = Wl + (size_t)(col0 + wn + fm) * K + fq * 8;
    const bf16_t* pb1l = Wl + (size_t)(col0 + wn + 16 + fm) * K + fq * 8;

    f32x4 acc[2][2] = {};

    bf16x8 ahA[2], alA[2], bhA[2], blA[2];
    bf16x8 ahB[2], alB[2], bhB[2], blB[2];

#define LOAD2(kt, ah, al, bh, bl) do {                              \
        int kk = (kt) * 32;                                         \
        ah[0] = *(const bf16x8*)(pa0h + kk);                        \
        ah[1] = *(const bf16x8*)(pa1h + kk);                        \
        al[0] = *(const bf16x8*)(pa0l + kk);                        \
        al[1] = *(const bf16x8*)(pa1l + kk);                        \
        bh[0] = *(const bf16x8*)(pb0h + kk);                        \
        bh[1] = *(const bf16x8*)(pb1h + kk);                        \
        bl[0] = *(const bf16x8*)(pb0l + kk);                        \
        bl[1] = *(const bf16x8*)(pb1l + kk);                        \
    } while (0)

#define COMP2(ah, al, bh, bl) do {                                  \
        _Pragma("unroll")                                           \
        for (int mi = 0; mi < 2; mi++)                              \
            _Pragma("unroll")                                       \
            for (int ni = 0; ni < 2; ni++) {                        \
                acc[mi][ni] = __builtin_amdgcn_mfma_f32_16x16x32_bf16(ah[mi], bh[ni], acc[mi][ni], 0, 0, 0); \
                acc[mi][ni] = __builtin_amdgcn_mfma_f32_16x16x32_bf16(ah[mi], bl[ni], acc[mi][ni], 0, 0, 0); \
                acc[mi][ni] = __builtin_amdgcn_mfma_f32_16x16x32_bf16(al[mi], bh[ni], acc[mi][ni], 0, 0, 0); \
            }                                                       \
    } while (0)

    const int KT = K >> 5;              // 4
    LOAD2(0, ahA, alA, bhA, blA);
#pragma unroll
    for (int kt = 0; kt < 4; kt += 2) {
        LOAD2(kt + 1, ahB, alB, bhB, blB);
        COMP2(ahA, alA, bhA, blA);
        if (kt + 2 < KT) LOAD2(kt + 2, ahA, alA, bhA, blA);
        COMP2(ahB, alB, bhB, blB);
    }
#undef LOAD2
#undef COMP2

#pragma unroll
    for (int mi = 0; mi < 2; mi++)
#pragma unroll
        for (int r = 0; r < 4; r++) {
            int grow = row0 + wm + mi * 16 + fq * 4 + r;
            if (grow < N) {
                float dr = dis[grow];
#pragma unroll
                for (int ni = 0; ni < 2; ni++)
                    Cb[(size_t)grow * D_H + col0 + wn + ni * 16 + fm] = (bf16_t)(dr * acc[mi][ni][r]);
            }
        }
}

// ---------------- aggregation ----------------
__global__ __launch_bounds__(256) void k_agg(const bf16_t* __restrict__ Hb,
                                             const float* __restrict__ dis,
                                             const int* __restrict__ off,
                                             const u16* __restrict__ csr16,
                                             const float4* __restrict__ bias4,
                                             float4* __restrict__ outF,
                                             bf16_t* __restrict__ outH,
                                             bf16_t* __restrict__ outL,
                                             int N, int mode) {
    const int half = threadIdx.x >> 5;
    const int lane = threadIdx.x & 31;
    const int node = blockIdx.x * 8 + half;
    if (node >= N) return;

    const size_t loff = (size_t)lane * 4;

    bf16x4 vs = *(const bf16x4*)(Hb + (size_t)node * D_H + loff);
    float4 a0 = make_float4((float)vs[0], (float)vs[1], (float)vs[2], (float)vs[3]);
    float4 a1 = {0,0,0,0}, a2 = {0,0,0,0}, a3 = {0,0,0,0};
    float4 a4 = {0,0,0,0}, a5 = {0,0,0,0}, a6 = {0,0,0,0}, a7 = {0,0,0,0};

    int p  = off[node];
    int p1 = off[node + 1];

    for (; p + 8 <= p1; p += 8) {
        int s0 = (int)csr16[p + 0], s1 = (int)csr16[p + 1];
        int s2 = (int)csr16[p + 2], s3 = (int)csr16[p + 3];
        int s4 = (int)csr16[p + 4], s5 = (int)csr16[p + 5];
        int s6 = (int)csr16[p + 6], s7 = (int)csr16[p + 7];
        bf16x4 h0 = *(const bf16x4*)(Hb + (size_t)s0 * D_H + loff);
        bf16x4 h1 = *(const bf16x4*)(Hb + (size_t)s1 * D_H + loff);
        bf16x4 h2 = *(const bf16x4*)(Hb + (size_t)s2 * D_H + loff);
        bf16x4 h3 = *(const bf16x4*)(Hb + (size_t)s3 * D_H + loff);
        bf16x4 h4 = *(const bf16x4*)(Hb + (size_t)s4 * D_H + loff);
        bf16x4 h5 = *(const bf16x4*)(Hb + (size_t)s5 * D_H + loff);
        bf16x4 h6 = *(const bf16x4*)(Hb + (size_t)s6 * D_H + loff);
        bf16x4 h7 = *(const bf16x4*)(Hb + (size_t)s7 * D_H + loff);
        a0.x += (float)h0[0]; a0.y += (float)h0[1]; a0.z += (float)h0[2]; a0.w += (float)h0[3];
        a1.x += (float)h1[0]; a1.y += (float)h1[1]; a1.z += (float)h1[2]; a1.w += (float)h1[3];
        a2.x += (float)h2[0]; a2.y += (float)h2[1]; a2.z += (float)h2[2]; a2.w += (float)h2[3];
        a3.x += (float)h3[0]; a3.y += (float)h3[1]; a3.z += (float)h3[2]; a3.w += (float)h3[3];
        a4.x += (float)h4[0]; a4.y += (float)h4[1]; a4.z += (float)h4[2]; a4.w += (float)h4[3];
        a5.x += (float)h5[0]; a5.y += (float)h5[1]; a5.z += (float)h5[2]; a5.w += (float)h5[3];
        a6.x += (float)h6[0]; a6.y += (float)h6[1]; a6.z += (float)h6[2]; a6.w += (float)h6[3];
        a7.x += (float)h7[0]; a7.y += (float)h7[1]; a7.z += (float)h7[2]; a7.w += (float)h7[3];
    }
    if (p + 4 <= p1) {
        int s0 = (int)csr16[p + 0], s1 = (int)csr16[p + 1];
        int s2 = (int)csr16[p + 2], s3 = (int)csr16[p + 3];
        bf16x4 h0 = *(const bf16x4*)(Hb + (size_t)s0 * D_H + loff);
        bf16x4 h1 = *(const bf16x4*)(Hb + (size_t)s1 * D_H + loff);
        bf16x4 h2 = *(const bf16x4*)(Hb + (size_t)s2 * D_H + loff);
        bf16x4 h3 = *(const bf16x4*)(Hb + (size_t)s3 * D_H + loff);
        a0.x += (float)h0[0]; a0.y += (float)h0[1]; a0.z += (float)h0[2]; a0.w += (float)h0[3];
        a1.x += (float)h1[0]; a1.y += (float)h1[1]; a1.z += (float)h1[2]; a1.w += (float)h1[3];
        a2.x += (float)h2[0]; a2.y += (float)h2[1]; a2.z += (float)h2[2]; a2.w += (float)h2[3];
        a3.x += (float)h3[0]; a3.y += (float)h3[1]; a3.z += (float)h3[2]; a3.w += (float)h3[3];
        p += 4;
    }
    for (; p < p1; p++) {
        int s0 = (int)csr16[p];
        bf16x4 h0 = *(const bf16x4*)(Hb + (size_t)s0 * D_H + loff);
        a0.x += (float)h0[0]; a0.y += (float)h0[1]; a0.z += (float)h0[2]; a0.w += (float)h0[3];
    }

    float4 sum;
    sum.x = ((a0.x + a1.x) + (a2.x + a3.x)) + ((a4.x + a5.x) + (a6.x + a7.x));
    sum.y = ((a0.y + a1.y) + (a2.y + a3.y)) + ((a4.y + a5.y) + (a6.y + a7.y));
    sum.z = ((a0.z + a1.z) + (a2.z + a3.z)) + ((a4.z + a5.z) + (a6.z + a7.z));
    sum.w = ((a0.w + a1.w) + (a2.w + a3.w)) + ((a4.w + a5.w) + (a6.w + a7.w));

    const float  di = dis[node];
    const float4 bv = bias4[lane];
    float vx = fmaf(di, sum.x, bv.x);
    float vy = fmaf(di, sum.y, bv.y);
    float vz = fmaf(di, sum.z, bv.z);
    float vw = fmaf(di, sum.w, bv.w);

    if (mode == 1) {
        vx = fmaxf(vx, 0.0f); vy = fmaxf(vy, 0.0f);
        vz = fmaxf(vz, 0.0f); vw = fmaxf(vw, 0.0f);
        bf16_t hx = (bf16_t)vx, hy = (bf16_t)vy, hz = (bf16_t)vz, hw = (bf16_t)vw;
        bf16_t lx = (bf16_t)(vx - (float)hx);
        bf16_t ly = (bf16_t)(vy - (float)hy);
        bf16_t lz = (bf16_t)(vz - (float)hz);
        bf16_t lw = (bf16_t)(vw - (float)hw);
        *(bf16x4*)(outH + (size_t)node * D_H + loff) = (bf16x4){hx, hy, hz, hw};
        *(bf16x4*)(outL + (size_t)node * D_H + loff) = (bf16x4){lx, ly, lz, lw};
    } else {
        outF[(size_t)node * 32 + lane] = make_float4(vx, vy, vz, vw);
    }
}

extern "C" void kernel_launch(void* const* d_in, const int* in_sizes, int n_in,
                              void* d_out, int out_size, void* d_ws, size_t ws_size,
                              hipStream_t stream) {
    const float* X  = (const float*)d_in[0];
    const int*   ei = (const int*)d_in[1];
    const float* W1 = (const float*)d_in[2];
    const float* b1 = (const float*)d_in[3];
    const float* W2 = (const float*)d_in[4];
    const float* b2 = (const float*)d_in[5];
    float* out = (float*)d_out;

    const int N  = in_sizes[0] / 256;   // 50000
    const int E  = in_sizes[1] / 2;     // 800000
    const int K1 = 256;

    const int* src = ei;
    const int* dst = ei + E;

    uintptr_t p = (uintptr_t)d_ws;
    auto carve = [&](size_t bytes) {
        uintptr_t q = p;
        p += (bytes + 255) & ~(size_t)255;
        return q;
    };
    int*    cnt   = (int*)carve((size_t)N * 4);
    int*    off   = (int*)carve((size_t)(N + 1) * 4);
    int*    bsums = (int*)carve(64 * 4);
    float*  dis   = (float*)carve((size_t)N * 4);
    u16*    rank  = (u16*)carve((size_t)E * 2);
    u16*    csr16 = (u16*)carve((size_t)E * 2);
    bf16_t* Hb    = (bf16_t*)carve((size_t)N * D_H * 2);
    bf16_t* X1h   = (bf16_t*)carve((size_t)N * D_H * 2);
    bf16_t* X1l   = (bf16_t*)carve((size_t)N * D_H * 2);
    bf16_t* W1h   = (bf16_t*)carve((size_t)K1 * D_H * 2);
    bf16_t* W1l   = (bf16_t*)carve((size_t)K1 * D_H * 2);
    bf16_t* W2h   = (bf16_t*)carve((size_t)D_H * D_H * 2);
    bf16_t* W2l   = (bf16_t*)carve((size_t)D_H * D_H * 2);

    const int nb = (N + 1023) / 1024;

    // graph preprocessing (+ weight prep fused into countrank's grid)
    hipMemsetAsync(cnt, 0, (size_t)N * 4, stream);
    const int gcr   = (E + 255) / 256;
    const int gprep = (K1 * 128 + D_H * 128 + 255) / 256;
    k_countrank<<<gcr + gprep, 256, 0, stream>>>(dst, cnt, rank, E, gcr,
                                                 W1, W1h, W1l, K1,
                                                 W2, W2h, W2l, D_H);
    k_scan1<<<nb, 1024, 0, stream>>>(cnt, off, bsums, dis, N);
    k_scan2<<<1, 64, 0, stream>>>(bsums, nb);
    k_scan3<<<nb, 1024, 0, stream>>>(off, bsums, N, E);

    const int gmm = ((N + 63) / 64) * 2;    // 1564 blocks (row x col split)
    const int gag = (N + 7) / 8;

    // layer 1 GEMM (LDS-free) with distributed CSR fill
    k_mm1fill<<<gmm, 256, 0, stream>>>(X, W1h, W1l, dis, Hb, N, K1,
                                       src, dst, off, rank, csr16, E, gmm * 256);
    k_agg<<<gag, 256, 0, stream>>>(Hb, dis, off, csr16,
                                   (const float4*)b1, nullptr, X1h, X1l, N, 1);

    // layer 2 (LDS-free)
    k_mm2<<<gmm, 256, 0, stream>>>(X1h, X1l, W2h, W2l, dis, Hb, N, D_H);
    k_agg<<<gag, 256, 0, stream>>>(Hb, dis, off, csr16,
                                   (const float4*)b2, (float4*)out, nullptr, nullptr, N, 0);
}

// Round 10
// 271.305 us; speedup vs baseline: 1.0880x; 1.0880x over previous
//
#include <hip/hip_runtime.h>
#include <hip/hip_bf16.h>
#include <stdint.h>

#define D_H 128

typedef __bf16 bf16_t;
typedef unsigned short u16;
typedef bf16_t bf16x8 __attribute__((ext_vector_type(8)));
typedef bf16_t bf16x4 __attribute__((ext_vector_type(4)));
typedef float  f32x4  __attribute__((ext_vector_type(4)));

// ---------------- degree count + rank capture + weight prep (fused) --------
__global__ void k_countrank(const int* __restrict__ dst, int* __restrict__ cnt,
                            u16* __restrict__ rank, int E, int crBlocks,
                            const float* __restrict__ W1, bf16_t* __restrict__ W1h,
                            bf16_t* __restrict__ W1l, int K1,
                            const float* __restrict__ W2, bf16_t* __restrict__ W2h,
                            bf16_t* __restrict__ W2l, int K2) {
    if ((int)blockIdx.x < crBlocks) {
        int e = blockIdx.x * 256 + threadIdx.x;
        if (e < E) rank[e] = (u16)atomicAdd(&cnt[dst[e]], 1);
        return;
    }
    int id = ((int)blockIdx.x - crBlocks) * 256 + threadIdx.x;
    int n1 = K1 * 128;
    if (id < n1) {
        int k = id >> 7, n = id & 127;
        float w = W1[id];
        bf16_t h = (bf16_t)w;
        W1h[(size_t)n * K1 + k] = h;
        W1l[(size_t)n * K1 + k] = (bf16_t)(w - (float)h);
    } else if (id < n1 + K2 * 128) {
        int id2 = id - n1;
        int k = id2 >> 7, n = id2 & 127;
        float w = W2[id2];
        bf16_t h = (bf16_t)w;
        W2h[(size_t)n * K2 + k] = h;
        W2l[(size_t)n * K2 + k] = (bf16_t)(w - (float)h);
    }
}

// ---------------- exclusive scan (3 kernels); scan1 also emits dis ----------
__global__ __launch_bounds__(1024) void k_scan1(const int* __restrict__ cnt,
                                                int* __restrict__ out,
                                                int* __restrict__ bsums,
                                                float* __restrict__ dis, int N) {
    __shared__ int tmp[1024];
    int t = threadIdx.x;
    int i = blockIdx.x * 1024 + t;
    int v = (i < N) ? cnt[i] : 0;
    if (i < N) dis[i] = 1.0f / sqrtf((float)(v + 1));
    tmp[t] = v;
    __syncthreads();
    for (int d = 1; d < 1024; d <<= 1) {
        int x = (t >= d) ? tmp[t - d] : 0;
        __syncthreads();
        tmp[t] += x;
        __syncthreads();
    }
    if (i < N) out[i] = tmp[t] - v;
    if (t == 1023) bsums[blockIdx.x] = tmp[t];
}

__global__ void k_scan2(int* __restrict__ bsums, int nb) {
    __shared__ int tmp[64];
    int t = threadIdx.x;
    int v = (t < nb) ? bsums[t] : 0;
    tmp[t] = v;
    __syncthreads();
    for (int d = 1; d < 64; d <<= 1) {
        int x = (t >= d) ? tmp[t - d] : 0;
        __syncthreads();
        tmp[t] += x;
        __syncthreads();
    }
    if (t < nb) bsums[t] = tmp[t] - v;
}

__global__ __launch_bounds__(1024) void k_scan3(int* __restrict__ off,
                                                const int* __restrict__ bsums,
                                                int N, int E) {
    int i = blockIdx.x * 1024 + threadIdx.x;
    if (i < N) off[i] += bsums[blockIdx.x];
    if (i == 0) off[N] = E;
}

// ---------------- MFMA GEMM tiles: BM=64, BN=64, 256 thr = 4 waves --------
// (round-8 structure, best measured). blockIdx: row0=(bx>>1)*64, col0=(bx&1)*64.
#define LDK 40
#define FILL_PER 2

// layer-1 (fp32 A, hi/lo split in-kernel) + distributed CSR fill
__global__ __launch_bounds__(256) void k_mm1fill(
        const float* __restrict__ Af,
        const bf16_t* __restrict__ Wh, const bf16_t* __restrict__ Wl,
        const float* __restrict__ dis, bf16_t* __restrict__ Cb,
        int N, int K,
        const int* __restrict__ src, const int* __restrict__ dst,
        const int* __restrict__ off, const u16* __restrict__ rank,
        u16* __restrict__ csr16, int E, int totThreads) {
    __shared__ bf16_t AsH[64][LDK];
    __shared__ bf16_t AsL[64][LDK];
    __shared__ bf16_t BsH[64][LDK];
    __shared__ bf16_t BsL[64][LDK];

    const int t    = threadIdx.x;
    const int lane = t & 63;
    const int wave = t >> 6;            // 0..3
    const int row0 = ((int)blockIdx.x >> 1) * 64;
    const int col0 = ((int)blockIdx.x & 1) * 64;
    const int wm   = (wave & 1) * 32;
    const int wn   = (wave >> 1) * 32;
    const int fm   = lane & 15;
    const int fq   = lane >> 4;

    // ---- fill prologue: resolve scatter addresses ----
    const int g = (int)blockIdx.x * 256 + t;
    int epos[FILL_PER];
    u16 esrc[FILL_PER];
#pragma unroll
    for (int i = 0; i < FILL_PER; i++) {
        int e = g + i * totThreads;
        if (e < E) {
            int d = dst[e];
            epos[i] = off[d] + (int)rank[e];
            esrc[i] = (u16)src[e];
        } else {
            epos[i] = -1;
            esrc[i] = 0;
        }
    }

    f32x4 acc[2][2] = {};

    for (int k0 = 0; k0 < K; k0 += 32) {
        __syncthreads();
        // stage A: 64 rows x 32 k fp32 = 512 float4; 2/thread, split hi/lo
#pragma unroll
        for (int i = 0; i < 2; i++) {
            int idx = t + i * 256;
            int r   = idx >> 3;
            int c4  = idx & 7;
            int gr  = row0 + r;
            float4 v = make_float4(0.f, 0.f, 0.f, 0.f);
            if (gr < N) v = *(const float4*)(Af + (size_t)gr * K + k0 + c4 * 4);
            bf16_t h0 = (bf16_t)v.x, h1 = (bf16_t)v.y, h2 = (bf16_t)v.z, h3 = (bf16_t)v.w;
            bf16_t l0 = (bf16_t)(v.x - (float)h0);
            bf16_t l1 = (bf16_t)(v.y - (float)h1);
            bf16_t l2 = (bf16_t)(v.z - (float)h2);
            bf16_t l3 = (bf16_t)(v.w - (float)h3);
            *(bf16x4*)&AsH[r][c4 * 4] = (bf16x4){h0, h1, h2, h3};
            *(bf16x4*)&AsL[r][c4 * 4] = (bf16x4){l0, l1, l2, l3};
        }
        // stage B: 64 cols x 32 k, 256 bf16x8 per plane; 1/thread per plane
        {
            int r  = t >> 2;
            int c8 = t & 3;
            *(bf16x8*)&BsH[r][c8 * 8] = *(const bf16x8*)(Wh + (size_t)(col0 + r) * K + k0 + c8 * 8);
            *(bf16x8*)&BsL[r][c8 * 8] = *(const bf16x8*)(Wl + (size_t)(col0 + r) * K + k0 + c8 * 8);
        }
        __syncthreads();

        bf16x8 ah[2], al[2], bh[2], bl[2];
#pragma unroll
        for (int i = 0; i < 2; i++) {
            ah[i] = *(const bf16x8*)&AsH[wm + i * 16 + fm][fq * 8];
            al[i] = *(const bf16x8*)&AsL[wm + i * 16 + fm][fq * 8];
            bh[i] = *(const bf16x8*)&BsH[wn + i * 16 + fm][fq * 8];
            bl[i] = *(const bf16x8*)&BsL[wn + i * 16 + fm][fq * 8];
        }
#pragma unroll
        for (int mi = 0; mi < 2; mi++)
#pragma unroll
            for (int ni = 0; ni < 2; ni++) {
                acc[mi][ni] = __builtin_amdgcn_mfma_f32_16x16x32_bf16(ah[mi], bh[ni], acc[mi][ni], 0, 0, 0);
                acc[mi][ni] = __builtin_amdgcn_mfma_f32_16x16x32_bf16(ah[mi], bl[ni], acc[mi][ni], 0, 0, 0);
                acc[mi][ni] = __builtin_amdgcn_mfma_f32_16x16x32_bf16(al[mi], bh[ni], acc[mi][ni], 0, 0, 0);
            }
    }

#pragma unroll
    for (int mi = 0; mi < 2; mi++)
#pragma unroll
        for (int r = 0; r < 4; r++) {
            int grow = row0 + wm + mi * 16 + fq * 4 + r;
            if (grow < N) {
                float dr = dis[grow];
#pragma unroll
                for (int ni = 0; ni < 2; ni++)
                    Cb[(size_t)grow * D_H + col0 + wn + ni * 16 + fm] = (bf16_t)(dr * acc[mi][ni][r]);
            }
        }

    // ---- fill epilogue: scattered 2B stores, fire and forget ----
#pragma unroll
    for (int i = 0; i < FILL_PER; i++)
        if (epos[i] >= 0) csr16[epos[i]] = esrc[i];
}

// layer-2 (bf16 hi/lo A)
__global__ __launch_bounds__(256) void k_mm2(const bf16_t* __restrict__ Ah,
                                             const bf16_t* __restrict__ Al,
                                             const bf16_t* __restrict__ Wh,
                                             const bf16_t* __restrict__ Wl,
                                             const float* __restrict__ dis,
                                             bf16_t* __restrict__ Cb,
                                             int N, int K) {
    __shared__ bf16_t AsH[64][LDK];
    __shared__ bf16_t AsL[64][LDK];
    __shared__ bf16_t BsH[64][LDK];
    __shared__ bf16_t BsL[64][LDK];

    const int t    = threadIdx.x;
    const int lane = t & 63;
    const int wave = t >> 6;
    const int row0 = ((int)blockIdx.x >> 1) * 64;
    const int col0 = ((int)blockIdx.x & 1) * 64;
    const int wm   = (wave & 1) * 32;
    const int wn   = (wave >> 1) * 32;
    const int fm   = lane & 15;
    const int fq   = lane >> 4;

    f32x4 acc[2][2] = {};

    for (int k0 = 0; k0 < K; k0 += 32) {
        __syncthreads();
        {
            int r  = t >> 2;
            int c8 = t & 3;
            int gr = row0 + r;
            bf16x8 vh = {}, vl = {};
            if (gr < N) {
                vh = *(const bf16x8*)(Ah + (size_t)gr * K + k0 + c8 * 8);
                vl = *(const bf16x8*)(Al + (size_t)gr * K + k0 + c8 * 8);
            }
            *(bf16x8*)&AsH[r][c8 * 8] = vh;
            *(bf16x8*)&AsL[r][c8 * 8] = vl;
        }
        {
            int r  = t >> 2;
            int c8 = t & 3;
            *(bf16x8*)&BsH[r][c8 * 8] = *(const bf16x8*)(Wh + (size_t)(col0 + r) * K + k0 + c8 * 8);
            *(bf16x8*)&BsL[r][c8 * 8] = *(const bf16x8*)(Wl + (size_t)(col0 + r) * K + k0 + c8 * 8);
        }
        __syncthreads();

        bf16x8 ah[2], al[2], bh[2], bl[2];
#pragma unroll
        for (int i = 0; i < 2; i++) {
            ah[i] = *(const bf16x8*)&AsH[wm + i * 16 + fm][fq * 8];
            al[i] = *(const bf16x8*)&AsL[wm + i * 16 + fm][fq * 8];
            bh[i] = *(const bf16x8*)&BsH[wn + i * 16 + fm][fq * 8];
            bl[i] = *(const bf16x8*)&BsL[wn + i * 16 + fm][fq * 8];
        }
#pragma unroll
        for (int mi = 0; mi < 2; mi++)
#pragma unroll
            for (int ni = 0; ni < 2; ni++) {
                acc[mi][ni] = __builtin_amdgcn_mfma_f32_16x16x32_bf16(ah[mi], bh[ni], acc[mi][ni], 0, 0, 0);
                acc[mi][ni] = __builtin_amdgcn_mfma_f32_16x16x32_bf16(ah[mi], bl[ni], acc[mi][ni], 0, 0, 0);
                acc[mi][ni] = __builtin_amdgcn_mfma_f32_16x16x32_bf16(al[mi], bh[ni], acc[mi][ni], 0, 0, 0);
            }
    }

#pragma unroll
    for (int mi = 0; mi < 2; mi++)
#pragma unroll
        for (int r = 0; r < 4; r++) {
            int grow = row0 + wm + mi * 16 + fq * 4 + r;
            if (grow < N) {
                float dr = dis[grow];
#pragma unroll
                for (int ni = 0; ni < 2; ni++)
                    Cb[(size_t)grow * D_H + col0 + wn + ni * 16 + fm] = (bf16_t)(dr * acc[mi][ni][r]);
            }
        }
}

// ---------------- aggregation, L2 feature-chunked ----------------
// 4 chunks x 32 features (64B/row): per-chunk gather working set = 3.2MB,
// fits each XCD's 4MB L2. Chunk-major grid; 8 lanes/node (bf16x4 = 8B),
// 32 nodes per 256-block, edge loop unrolled x8 (8 streams/node).
__global__ __launch_bounds__(256) void k_agg(const bf16_t* __restrict__ Hb,
                                             const float* __restrict__ dis,
                                             const int* __restrict__ off,
                                             const u16* __restrict__ csr16,
                                             const float4* __restrict__ bias4,
                                             float4* __restrict__ outF,
                                             bf16_t* __restrict__ outH,
                                             bf16_t* __restrict__ outL,
                                             int N, int mode, int nbase) {
    const int chunk = (int)blockIdx.x / nbase;      // 0..3
    const int nblk  = (int)blockIdx.x % nbase;
    const int slot  = threadIdx.x >> 3;             // 0..31
    const int lane8 = threadIdx.x & 7;              // 0..7
    const int node  = nblk * 32 + slot;
    if (node >= N) return;

    const int  fidx = chunk * 32 + lane8 * 4;       // feature index (x4)
    const bf16_t* Hc = Hb + fidx;

    bf16x4 vs = *(const bf16x4*)(Hc + (size_t)node * D_H);
    float4 a0 = make_float4((float)vs[0], (float)vs[1], (float)vs[2], (float)vs[3]);
    float4 a1 = {0,0,0,0}, a2 = {0,0,0,0}, a3 = {0,0,0,0};
    float4 a4 = {0,0,0,0}, a5 = {0,0,0,0}, a6 = {0,0,0,0}, a7 = {0,0,0,0};

    int p  = off[node];
    int p1 = off[node + 1];

    for (; p + 8 <= p1; p += 8) {
        int s0 = (int)csr16[p + 0], s1 = (int)csr16[p + 1];
        int s2 = (int)csr16[p + 2], s3 = (int)csr16[p + 3];
        int s4 = (int)csr16[p + 4], s5 = (int)csr16[p + 5];
        int s6 = (int)csr16[p + 6], s7 = (int)csr16[p + 7];
        bf16x4 h0 = *(const bf16x4*)(Hc + (size_t)s0 * D_H);
        bf16x4 h1 = *(const bf16x4*)(Hc + (size_t)s1 * D_H);
        bf16x4 h2 = *(const bf16x4*)(Hc + (size_t)s2 * D_H);
        bf16x4 h3 = *(const bf16x4*)(Hc + (size_t)s3 * D_H);
        bf16x4 h4 = *(const bf16x4*)(Hc + (size_t)s4 * D_H);
        bf16x4 h5 = *(const bf16x4*)(Hc + (size_t)s5 * D_H);
        bf16x4 h6 = *(const bf16x4*)(Hc + (size_t)s6 * D_H);
        bf16x4 h7 = *(const bf16x4*)(Hc + (size_t)s7 * D_H);
        a0.x += (float)h0[0]; a0.y += (float)h0[1]; a0.z += (float)h0[2]; a0.w += (float)h0[3];
        a1.x += (float)h1[0]; a1.y += (float)h1[1]; a1.z += (float)h1[2]; a1.w += (float)h1[3];
        a2.x += (float)h2[0]; a2.y += (float)h2[1]; a2.z += (float)h2[2]; a2.w += (float)h2[3];
        a3.x += (float)h3[0]; a3.y += (float)h3[1]; a3.z += (float)h3[2]; a3.w += (float)h3[3];
        a4.x += (float)h4[0]; a4.y += (float)h4[1]; a4.z += (float)h4[2]; a4.w += (float)h4[3];
        a5.x += (float)h5[0]; a5.y += (float)h5[1]; a5.z += (float)h5[2]; a5.w += (float)h5[3];
        a6.x += (float)h6[0]; a6.y += (float)h6[1]; a6.z += (float)h6[2]; a6.w += (float)h6[3];
        a7.x += (float)h7[0]; a7.y += (float)h7[1]; a7.z += (float)h7[2]; a7.w += (float)h7[3];
    }
    if (p + 4 <= p1) {
        int s0 = (int)csr16[p + 0], s1 = (int)csr16[p + 1];
        int s2 = (int)csr16[p + 2], s3 = (int)csr16[p + 3];
        bf16x4 h0 = *(const bf16x4*)(Hc + (size_t)s0 * D_H);
        bf16x4 h1 = *(const bf16x4*)(Hc + (size_t)s1 * D_H);
        bf16x4 h2 = *(const bf16x4*)(Hc + (size_t)s2 * D_H);
        bf16x4 h3 = *(const bf16x4*)(Hc + (size_t)s3 * D_H);
        a0.x += (float)h0[0]; a0.y += (float)h0[1]; a0.z += (float)h0[2]; a0.w += (float)h0[3];
        a1.x += (float)h1[0]; a1.y += (float)h1[1]; a1.z += (float)h1[2]; a1.w += (float)h1[3];
        a2.x += (float)h2[0]; a2.y += (float)h2[1]; a2.z += (float)h2[2]; a2.w += (float)h2[3];
        a3.x += (float)h3[0]; a3.y += (float)h3[1]; a3.z += (float)h3[2]; a3.w += (float)h3[3];
        p += 4;
    }
    for (; p < p1; p++) {
        int s0 = (int)csr16[p];
        bf16x4 h0 = *(const bf16x4*)(Hc + (size_t)s0 * D_H);
        a0.x += (float)h0[0]; a0.y += (float)h0[1]; a0.z += (float)h0[2]; a0.w += (float)h0[3];
    }

    float4 sum;
    sum.x = ((a0.x + a1.x) + (a2.x + a3.x)) + ((a4.x + a5.x) + (a6.x + a7.x));
    sum.y = ((a0.y + a1.y) + (a2.y + a3.y)) + ((a4.y + a5.y) + (a6.y + a7.y));
    sum.z = ((a0.z + a1.z) + (a2.z + a3.z)) + ((a4.z + a5.z) + (a6.z + a7.z));
    sum.w = ((a0.w + a1.w) + (a2.w + a3.w)) + ((a4.w + a5.w) + (a6.w + a7.w));

    const float  di = dis[node];
    const float4 bv = bias4[chunk * 8 + lane8];
    float vx = fmaf(di, sum.x, bv.x);
    float vy = fmaf(di, sum.y, bv.y);
    float vz = fmaf(di, sum.z, bv.z);
    float vw = fmaf(di, sum.w, bv.w);

    if (mode == 1) {
        vx = fmaxf(vx, 0.0f); vy = fmaxf(vy, 0.0f);
        vz = fmaxf(vz, 0.0f); vw = fmaxf(vw, 0.0f);
        bf16_t hx = (bf16_t)vx, hy = (bf16_t)vy, hz = (bf16_t)vz, hw = (bf16_t)vw;
        bf16_t lx = (bf16_t)(vx - (float)hx);
        bf16_t ly = (bf16_t)(vy - (float)hy);
        bf16_t lz = (bf16_t)(vz - (float)hz);
        bf16_t lw = (bf16_t)(vw - (float)hw);
        *(bf16x4*)(outH + (size_t)node * D_H + fidx) = (bf16x4){hx, hy, hz, hw};
        *(bf16x4*)(outL + (size_t)node * D_H + fidx) = (bf16x4){lx, ly, lz, lw};
    } else {
        outF[(size_t)node * 32 + chunk * 8 + lane8] = make_float4(vx, vy, vz, vw);
    }
}

extern "C" void kernel_launch(void* const* d_in, const int* in_sizes, int n_in,
                              void* d_out, int out_size, void* d_ws, size_t ws_size,
                              hipStream_t stream) {
    const float* X  = (const float*)d_in[0];
    const int*   ei = (const int*)d_in[1];
    const float* W1 = (const float*)d_in[2];
    const float* b1 = (const float*)d_in[3];
    const float* W2 = (const float*)d_in[4];
    const float* b2 = (const float*)d_in[5];
    float* out = (float*)d_out;

    const int N  = in_sizes[0] / 256;   // 50000
    const int E  = in_sizes[1] / 2;     // 800000
    const int K1 = 256;

    const int* src = ei;
    const int* dst = ei + E;

    uintptr_t p = (uintptr_t)d_ws;
    auto carve = [&](size_t bytes) {
        uintptr_t q = p;
        p += (bytes + 255) & ~(size_t)255;
        return q;
    };
    int*    cnt   = (int*)carve((size_t)N * 4);
    int*    off   = (int*)carve((size_t)(N + 1) * 4);
    int*    bsums = (int*)carve(64 * 4);
    float*  dis   = (float*)carve((size_t)N * 4);
    u16*    rank  = (u16*)carve((size_t)E * 2);
    u16*    csr16 = (u16*)carve((size_t)E * 2);
    bf16_t* Hb    = (bf16_t*)carve((size_t)N * D_H * 2);
    bf16_t* X1h   = (bf16_t*)carve((size_t)N * D_H * 2);
    bf16_t* X1l   = (bf16_t*)carve((size_t)N * D_H * 2);
    bf16_t* W1h   = (bf16_t*)carve((size_t)K1 * D_H * 2);
    bf16_t* W1l   = (bf16_t*)carve((size_t)K1 * D_H * 2);
    bf16_t* W2h   = (bf16_t*)carve((size_t)D_H * D_H * 2);
    bf16_t* W2l   = (bf16_t*)carve((size_t)D_H * D_H * 2);

    const int nb = (N + 1023) / 1024;

    // graph preprocessing (+ weight prep fused into countrank's grid)
    hipMemsetAsync(cnt, 0, (size_t)N * 4, stream);
    const int gcr   = (E + 255) / 256;
    const int gprep = (K1 * 128 + D_H * 128 + 255) / 256;
    k_countrank<<<gcr + gprep, 256, 0, stream>>>(dst, cnt, rank, E, gcr,
                                                 W1, W1h, W1l, K1,
                                                 W2, W2h, W2l, D_H);
    k_scan1<<<nb, 1024, 0, stream>>>(cnt, off, bsums, dis, N);
    k_scan2<<<1, 64, 0, stream>>>(bsums, nb);
    k_scan3<<<nb, 1024, 0, stream>>>(off, bsums, N, E);

    const int gmm   = ((N + 63) / 64) * 2;   // 1564 blocks (row x col split)
    const int nbase = (N + 31) / 32;         // agg blocks per chunk
    const int gag   = nbase * 4;             // 4 feature chunks, chunk-major

    // layer 1 GEMM with distributed CSR fill
    k_mm1fill<<<gmm, 256, 0, stream>>>(X, W1h, W1l, dis, Hb, N, K1,
                                       src, dst, off, rank, csr16, E, gmm * 256);
    k_agg<<<gag, 256, 0, stream>>>(Hb, dis, off, csr16,
                                   (const float4*)b1, nullptr, X1h, X1l, N, 1, nbase);

    // layer 2
    k_mm2<<<gmm, 256, 0, stream>>>(X1h, X1l, W2h, W2l, dis, Hb, N, D_H);
    k_agg<<<gag, 256, 0, stream>>>(Hb, dis, off, csr16,
                                   (const float4*)b2, (float4*)out, nullptr, nullptr, N, 0, nbase);
}

// Round 11
// 269.486 us; speedup vs baseline: 1.0953x; 1.0067x over previous
//
#include <hip/hip_runtime.h>
#include <hip/hip_bf16.h>
#include <stdint.h>

#define D_H 128

typedef __bf16 bf16_t;
typedef unsigned short u16;
typedef bf16_t bf16x8 __attribute__((ext_vector_type(8)));
typedef bf16_t bf16x4 __attribute__((ext_vector_type(4)));
typedef float  f32x4  __attribute__((ext_vector_type(4)));

// ---------------- degree count + rank capture + weight prep (fused) --------
__global__ void k_countrank(const int* __restrict__ dst, int* __restrict__ cnt,
                            u16* __restrict__ rank, int E, int crBlocks,
                            const float* __restrict__ W1, bf16_t* __restrict__ W1h,
                            bf16_t* __restrict__ W1l, int K1,
                            const float* __restrict__ W2, bf16_t* __restrict__ W2h,
                            bf16_t* __restrict__ W2l, int K2) {
    if ((int)blockIdx.x < crBlocks) {
        int e = blockIdx.x * 256 + threadIdx.x;
        if (e < E) rank[e] = (u16)atomicAdd(&cnt[dst[e]], 1);
        return;
    }
    int id = ((int)blockIdx.x - crBlocks) * 256 + threadIdx.x;
    int n1 = K1 * 128;
    if (id < n1) {
        int k = id >> 7, n = id & 127;
        float w = W1[id];
        bf16_t h = (bf16_t)w;
        W1h[(size_t)n * K1 + k] = h;
        W1l[(size_t)n * K1 + k] = (bf16_t)(w - (float)h);
    } else if (id < n1 + K2 * 128) {
        int id2 = id - n1;
        int k = id2 >> 7, n = id2 & 127;
        float w = W2[id2];
        bf16_t h = (bf16_t)w;
        W2h[(size_t)n * K2 + k] = h;
        W2l[(size_t)n * K2 + k] = (bf16_t)(w - (float)h);
    }
}

// ---------------- exclusive scan (3 kernels); scan1 also emits dis ----------
__global__ __launch_bounds__(1024) void k_scan1(const int* __restrict__ cnt,
                                                int* __restrict__ out,
                                                int* __restrict__ bsums,
                                                float* __restrict__ dis, int N) {
    __shared__ int tmp[1024];
    int t = threadIdx.x;
    int i = blockIdx.x * 1024 + t;
    int v = (i < N) ? cnt[i] : 0;
    if (i < N) dis[i] = 1.0f / sqrtf((float)(v + 1));
    tmp[t] = v;
    __syncthreads();
    for (int d = 1; d < 1024; d <<= 1) {
        int x = (t >= d) ? tmp[t - d] : 0;
        __syncthreads();
        tmp[t] += x;
        __syncthreads();
    }
    if (i < N) out[i] = tmp[t] - v;
    if (t == 1023) bsums[blockIdx.x] = tmp[t];
}

__global__ void k_scan2(int* __restrict__ bsums, int nb) {
    __shared__ int tmp[64];
    int t = threadIdx.x;
    int v = (t < nb) ? bsums[t] : 0;
    tmp[t] = v;
    __syncthreads();
    for (int d = 1; d < 64; d <<= 1) {
        int x = (t >= d) ? tmp[t - d] : 0;
        __syncthreads();
        tmp[t] += x;
        __syncthreads();
    }
    if (t < nb) bsums[t] = tmp[t] - v;
}

__global__ __launch_bounds__(1024) void k_scan3(int* __restrict__ off,
                                                const int* __restrict__ bsums,
                                                int N, int E) {
    int i = blockIdx.x * 1024 + threadIdx.x;
    if (i < N) off[i] += bsums[blockIdx.x];
    if (i == 0) off[N] = E;
}

// ---------------- MFMA GEMM tiles: BM=64, BN=64, 256 thr = 4 waves --------
// Round-8 structure + global->register prefetch: tile k+1's loads are issued
// right after tile k's LDS store, so HBM latency overlaps compute + barriers.
#define LDK 40
#define FILL_PER 2

// layer-1 (fp32 A, hi/lo split in-kernel) + distributed CSR fill
__global__ __launch_bounds__(256) void k_mm1fill(
        const float* __restrict__ Af,
        const bf16_t* __restrict__ Wh, const bf16_t* __restrict__ Wl,
        const float* __restrict__ dis, bf16_t* __restrict__ Cb,
        int N, int K,
        const int* __restrict__ src, const int* __restrict__ dst,
        const int* __restrict__ off, const u16* __restrict__ rank,
        u16* __restrict__ csr16, int E, int totThreads) {
    __shared__ bf16_t AsH[64][LDK];
    __shared__ bf16_t AsL[64][LDK];
    __shared__ bf16_t BsH[64][LDK];
    __shared__ bf16_t BsL[64][LDK];

    const int t    = threadIdx.x;
    const int lane = t & 63;
    const int wave = t >> 6;            // 0..3
    const int row0 = ((int)blockIdx.x >> 1) * 64;
    const int col0 = ((int)blockIdx.x & 1) * 64;
    const int wm   = (wave & 1) * 32;
    const int wn   = (wave >> 1) * 32;
    const int fm   = lane & 15;
    const int fq   = lane >> 4;

    // ---- fill prologue: resolve scatter addresses ----
    const int g = (int)blockIdx.x * 256 + t;
    int epos[FILL_PER];
    u16 esrc[FILL_PER];
#pragma unroll
    for (int i = 0; i < FILL_PER; i++) {
        int e = g + i * totThreads;
        if (e < E) {
            int d = dst[e];
            epos[i] = off[d] + (int)rank[e];
            esrc[i] = (u16)src[e];
        } else {
            epos[i] = -1;
            esrc[i] = 0;
        }
    }

    // staging thread->element map
    const int ar0 = t >> 3;             // A rows 0..31
    const int ar1 = (t >> 3) + 32;      // A rows 32..63
    const int ac4 = t & 7;
    const int br  = t >> 2;             // B row 0..63
    const int bc8 = t & 3;
    const int gr0 = row0 + ar0;
    const int gr1 = row0 + ar1;

    float4 rA0, rA1;
    bf16x8 rBh, rBl;
    const float4 fz = make_float4(0.f, 0.f, 0.f, 0.f);

    auto gload = [&](int k0) {
        rA0 = (gr0 < N) ? *(const float4*)(Af + (size_t)gr0 * K + k0 + ac4 * 4) : fz;
        rA1 = (gr1 < N) ? *(const float4*)(Af + (size_t)gr1 * K + k0 + ac4 * 4) : fz;
        rBh = *(const bf16x8*)(Wh + (size_t)(col0 + br) * K + k0 + bc8 * 8);
        rBl = *(const bf16x8*)(Wl + (size_t)(col0 + br) * K + k0 + bc8 * 8);
    };
    auto lstore = [&]() {
        float4 v = rA0;
        bf16_t h0 = (bf16_t)v.x, h1 = (bf16_t)v.y, h2 = (bf16_t)v.z, h3 = (bf16_t)v.w;
        *(bf16x4*)&AsH[ar0][ac4 * 4] = (bf16x4){h0, h1, h2, h3};
        *(bf16x4*)&AsL[ar0][ac4 * 4] = (bf16x4){(bf16_t)(v.x - (float)h0), (bf16_t)(v.y - (float)h1),
                                                (bf16_t)(v.z - (float)h2), (bf16_t)(v.w - (float)h3)};
        v = rA1;
        h0 = (bf16_t)v.x; h1 = (bf16_t)v.y; h2 = (bf16_t)v.z; h3 = (bf16_t)v.w;
        *(bf16x4*)&AsH[ar1][ac4 * 4] = (bf16x4){h0, h1, h2, h3};
        *(bf16x4*)&AsL[ar1][ac4 * 4] = (bf16x4){(bf16_t)(v.x - (float)h0), (bf16_t)(v.y - (float)h1),
                                                (bf16_t)(v.z - (float)h2), (bf16_t)(v.w - (float)h3)};
        *(bf16x8*)&BsH[br][bc8 * 8] = rBh;
        *(bf16x8*)&BsL[br][bc8 * 8] = rBl;
    };

    f32x4 acc[2][2] = {};

    gload(0);
    for (int k0 = 0; k0 < K; k0 += 32) {
        __syncthreads();                // previous tile's consumers done
        lstore();
        if (k0 + 32 < K) gload(k0 + 32);   // prefetch next tile (latency hidden)
        __syncthreads();                // LDS tile ready

        bf16x8 ah[2], al[2], bh[2], bl[2];
#pragma unroll
        for (int i = 0; i < 2; i++) {
            ah[i] = *(const bf16x8*)&AsH[wm + i * 16 + fm][fq * 8];
            al[i] = *(const bf16x8*)&AsL[wm + i * 16 + fm][fq * 8];
            bh[i] = *(const bf16x8*)&BsH[wn + i * 16 + fm][fq * 8];
            bl[i] = *(const bf16x8*)&BsL[wn + i * 16 + fm][fq * 8];
        }
#pragma unroll
        for (int mi = 0; mi < 2; mi++)
#pragma unroll
            for (int ni = 0; ni < 2; ni++) {
                acc[mi][ni] = __builtin_amdgcn_mfma_f32_16x16x32_bf16(ah[mi], bh[ni], acc[mi][ni], 0, 0, 0);
                acc[mi][ni] = __builtin_amdgcn_mfma_f32_16x16x32_bf16(ah[mi], bl[ni], acc[mi][ni], 0, 0, 0);
                acc[mi][ni] = __builtin_amdgcn_mfma_f32_16x16x32_bf16(al[mi], bh[ni], acc[mi][ni], 0, 0, 0);
            }
    }

#pragma unroll
    for (int mi = 0; mi < 2; mi++)
#pragma unroll
        for (int r = 0; r < 4; r++) {
            int grow = row0 + wm + mi * 16 + fq * 4 + r;
            if (grow < N) {
                float dr = dis[grow];
#pragma unroll
                for (int ni = 0; ni < 2; ni++)
                    Cb[(size_t)grow * D_H + col0 + wn + ni * 16 + fm] = (bf16_t)(dr * acc[mi][ni][r]);
            }
        }

    // ---- fill epilogue: scattered 2B stores, fire and forget ----
#pragma unroll
    for (int i = 0; i < FILL_PER; i++)
        if (epos[i] >= 0) csr16[epos[i]] = esrc[i];
}

// layer-2 (bf16 hi/lo A) with register prefetch
__global__ __launch_bounds__(256) void k_mm2(const bf16_t* __restrict__ Ah,
                                             const bf16_t* __restrict__ Al,
                                             const bf16_t* __restrict__ Wh,
                                             const bf16_t* __restrict__ Wl,
                                             const float* __restrict__ dis,
                                             bf16_t* __restrict__ Cb,
                                             int N, int K) {
    __shared__ bf16_t AsH[64][LDK];
    __shared__ bf16_t AsL[64][LDK];
    __shared__ bf16_t BsH[64][LDK];
    __shared__ bf16_t BsL[64][LDK];

    const int t    = threadIdx.x;
    const int lane = t & 63;
    const int wave = t >> 6;
    const int row0 = ((int)blockIdx.x >> 1) * 64;
    const int col0 = ((int)blockIdx.x & 1) * 64;
    const int wm   = (wave & 1) * 32;
    const int wn   = (wave >> 1) * 32;
    const int fm   = lane & 15;
    const int fq   = lane >> 4;

    const int r8  = t >> 2;
    const int c8  = t & 3;
    const int gr  = row0 + r8;

    bf16x8 rAh, rAl, rBh, rBl;
    auto gload = [&](int k0) {
        bf16x8 z = {};
        rAh = (gr < N) ? *(const bf16x8*)(Ah + (size_t)gr * K + k0 + c8 * 8) : z;
        rAl = (gr < N) ? *(const bf16x8*)(Al + (size_t)gr * K + k0 + c8 * 8) : z;
        rBh = *(const bf16x8*)(Wh + (size_t)(col0 + r8) * K + k0 + c8 * 8);
        rBl = *(const bf16x8*)(Wl + (size_t)(col0 + r8) * K + k0 + c8 * 8);
    };
    auto lstore = [&]() {
        *(bf16x8*)&AsH[r8][c8 * 8] = rAh;
        *(bf16x8*)&AsL[r8][c8 * 8] = rAl;
        *(bf16x8*)&BsH[r8][c8 * 8] = rBh;
        *(bf16x8*)&BsL[r8][c8 * 8] = rBl;
    };

    f32x4 acc[2][2] = {};

    gload(0);
    for (int k0 = 0; k0 < K; k0 += 32) {
        __syncthreads();
        lstore();
        if (k0 + 32 < K) gload(k0 + 32);
        __syncthreads();

        bf16x8 ah[2], al[2], bh[2], bl[2];
#pragma unroll
        for (int i = 0; i < 2; i++) {
            ah[i] = *(const bf16x8*)&AsH[wm + i * 16 + fm][fq * 8];
            al[i] = *(const bf16x8*)&AsL[wm + i * 16 + fm][fq * 8];
            bh[i] = *(const bf16x8*)&BsH[wn + i * 16 + fm][fq * 8];
            bl[i] = *(const bf16x8*)&BsL[wn + i * 16 + fm][fq * 8];
        }
#pragma unroll
        for (int mi = 0; mi < 2; mi++)
#pragma unroll
            for (int ni = 0; ni < 2; ni++) {
                acc[mi][ni] = __builtin_amdgcn_mfma_f32_16x16x32_bf16(ah[mi], bh[ni], acc[mi][ni], 0, 0, 0);
                acc[mi][ni] = __builtin_amdgcn_mfma_f32_16x16x32_bf16(ah[mi], bl[ni], acc[mi][ni], 0, 0, 0);
                acc[mi][ni] = __builtin_amdgcn_mfma_f32_16x16x32_bf16(al[mi], bh[ni], acc[mi][ni], 0, 0, 0);
            }
    }

#pragma unroll
    for (int mi = 0; mi < 2; mi++)
#pragma unroll
        for (int r = 0; r < 4; r++) {
            int grow = row0 + wm + mi * 16 + fq * 4 + r;
            if (grow < N) {
                float dr = dis[grow];
#pragma unroll
                for (int ni = 0; ni < 2; ni++)
                    Cb[(size_t)grow * D_H + col0 + wn + ni * 16 + fm] = (bf16_t)(dr * acc[mi][ni][r]);
            }
        }
}

// ---------------- aggregation ----------------
// 16 lanes/node x bf16x8 (16B/lane, full 256B row per 16-lane group):
// half the vmem requests of the 32-lane version at identical bytes.
// 16 nodes per 256-block (4 nodes/wave), edge loop unrolled x4
// -> 16 independent row gathers in flight per wave.
__global__ __launch_bounds__(256) void k_agg(const bf16_t* __restrict__ Hb,
                                             const float* __restrict__ dis,
                                             const int* __restrict__ off,
                                             const u16* __restrict__ csr16,
                                             const float4* __restrict__ bias4,
                                             float4* __restrict__ outF,
                                             bf16_t* __restrict__ outH,
                                             bf16_t* __restrict__ outL,
                                             int N, int mode) {
    const int slot = threadIdx.x >> 4;           // 0..15: node slot
    const int lane = threadIdx.x & 15;           // feature group (8 bf16 = 16B)
    const int node = blockIdx.x * 16 + slot;
    if (node >= N) return;

    const bf16_t* Hrow = Hb + (size_t)lane * 8;

    float a0[8], a1[8], a2[8], a3[8];
    {
        bf16x8 v = *(const bf16x8*)(Hrow + (size_t)node * D_H);
#pragma unroll
        for (int j = 0; j < 8; j++) { a0[j] = (float)v[j]; a1[j] = 0.f; a2[j] = 0.f; a3[j] = 0.f; }
    }

    int p  = off[node];
    int p1 = off[node + 1];

    for (; p + 4 <= p1; p += 4) {
        int s0 = (int)csr16[p + 0], s1 = (int)csr16[p + 1];
        int s2 = (int)csr16[p + 2], s3 = (int)csr16[p + 3];
        bf16x8 h0 = *(const bf16x8*)(Hrow + (size_t)s0 * D_H);
        bf16x8 h1 = *(const bf16x8*)(Hrow + (size_t)s1 * D_H);
        bf16x8 h2 = *(const bf16x8*)(Hrow + (size_t)s2 * D_H);
        bf16x8 h3 = *(const bf16x8*)(Hrow + (size_t)s3 * D_H);
#pragma unroll
        for (int j = 0; j < 8; j++) {
            a0[j] += (float)h0[j];
            a1[j] += (float)h1[j];
            a2[j] += (float)h2[j];
            a3[j] += (float)h3[j];
        }
    }
    if (p + 2 <= p1) {
        int s0 = (int)csr16[p + 0], s1 = (int)csr16[p + 1];
        bf16x8 h0 = *(const bf16x8*)(Hrow + (size_t)s0 * D_H);
        bf16x8 h1 = *(const bf16x8*)(Hrow + (size_t)s1 * D_H);
#pragma unroll
        for (int j = 0; j < 8; j++) { a0[j] += (float)h0[j]; a1[j] += (float)h1[j]; }
        p += 2;
    }
    if (p < p1) {
        int s0 = (int)csr16[p];
        bf16x8 h0 = *(const bf16x8*)(Hrow + (size_t)s0 * D_H);
#pragma unroll
        for (int j = 0; j < 8; j++) a2[j] += (float)h0[j];
    }

    float sum[8];
#pragma unroll
    for (int j = 0; j < 8; j++) sum[j] = (a0[j] + a1[j]) + (a2[j] + a3[j]);

    const float  di = dis[node];
    const float4 b0 = bias4[lane * 2];
    const float4 b1 = bias4[lane * 2 + 1];
    float v0 = fmaf(di, sum[0], b0.x), v1 = fmaf(di, sum[1], b0.y);
    float v2 = fmaf(di, sum[2], b0.z), v3 = fmaf(di, sum[3], b0.w);
    float v4 = fmaf(di, sum[4], b1.x), v5 = fmaf(di, sum[5], b1.y);
    float v6 = fmaf(di, sum[6], b1.z), v7 = fmaf(di, sum[7], b1.w);

    if (mode == 1) {
        v0 = fmaxf(v0, 0.f); v1 = fmaxf(v1, 0.f); v2 = fmaxf(v2, 0.f); v3 = fmaxf(v3, 0.f);
        v4 = fmaxf(v4, 0.f); v5 = fmaxf(v5, 0.f); v6 = fmaxf(v6, 0.f); v7 = fmaxf(v7, 0.f);
        bf16_t h0 = (bf16_t)v0, h1 = (bf16_t)v1, h2 = (bf16_t)v2, h3 = (bf16_t)v3;
        bf16_t h4 = (bf16_t)v4, h5 = (bf16_t)v5, h6 = (bf16_t)v6, h7 = (bf16_t)v7;
        *(bf16x8*)(outH + (size_t)node * D_H + lane * 8) =
            (bf16x8){h0, h1, h2, h3, h4, h5, h6, h7};
        *(bf16x8*)(outL + (size_t)node * D_H + lane * 8) =
            (bf16x8){(bf16_t)(v0 - (float)h0), (bf16_t)(v1 - (float)h1),
                     (bf16_t)(v2 - (float)h2), (bf16_t)(v3 - (float)h3),
                     (bf16_t)(v4 - (float)h4), (bf16_t)(v5 - (float)h5),
                     (bf16_t)(v6 - (float)h6), (bf16_t)(v7 - (float)h7)};
    } else {
        outF[(size_t)node * 32 + lane * 2]     = make_float4(v0, v1, v2, v3);
        outF[(size_t)node * 32 + lane * 2 + 1] = make_float4(v4, v5, v6, v7);
    }
}

extern "C" void kernel_launch(void* const* d_in, const int* in_sizes, int n_in,
                              void* d_out, int out_size, void* d_ws, size_t ws_size,
                              hipStream_t stream) {
    const float* X  = (const float*)d_in[0];
    const int*   ei = (const int*)d_in[1];
    const float* W1 = (const float*)d_in[2];
    const float* b1 = (const float*)d_in[3];
    const float* W2 = (const float*)d_in[4];
    const float* b2 = (const float*)d_in[5];
    float* out = (float*)d_out;

    const int N  = in_sizes[0] / 256;   // 50000
    const int E  = in_sizes[1] / 2;     // 800000
    const int K1 = 256;

    const int* src = ei;
    const int* dst = ei + E;

    uintptr_t p = (uintptr_t)d_ws;
    auto carve = [&](size_t bytes) {
        uintptr_t q = p;
        p += (bytes + 255) & ~(size_t)255;
        return q;
    };
    int*    cnt   = (int*)carve((size_t)N * 4);
    int*    off   = (int*)carve((size_t)(N + 1) * 4);
    int*    bsums = (int*)carve(64 * 4);
    float*  dis   = (float*)carve((size_t)N * 4);
    u16*    rank  = (u16*)carve((size_t)E * 2);
    u16*    csr16 = (u16*)carve((size_t)E * 2);
    bf16_t* Hb    = (bf16_t*)carve((size_t)N * D_H * 2);
    bf16_t* X1h   = (bf16_t*)carve((size_t)N * D_H * 2);
    bf16_t* X1l   = (bf16_t*)carve((size_t)N * D_H * 2);
    bf16_t* W1h   = (bf16_t*)carve((size_t)K1 * D_H * 2);
    bf16_t* W1l   = (bf16_t*)carve((size_t)K1 * D_H * 2);
    bf16_t* W2h   = (bf16_t*)carve((size_t)D_H * D_H * 2);
    bf16_t* W2l   = (bf16_t*)carve((size_t)D_H * D_H * 2);

    const int nb = (N + 1023) / 1024;

    // graph preprocessing (+ weight prep fused into countrank's grid)
    hipMemsetAsync(cnt, 0, (size_t)N * 4, stream);
    const int gcr   = (E + 255) / 256;
    const int gprep = (K1 * 128 + D_H * 128 + 255) / 256;
    k_countrank<<<gcr + gprep, 256, 0, stream>>>(dst, cnt, rank, E, gcr,
                                                 W1, W1h, W1l, K1,
                                                 W2, W2h, W2l, D_H);
    k_scan1<<<nb, 1024, 0, stream>>>(cnt, off, bsums, dis, N);
    k_scan2<<<1, 64, 0, stream>>>(bsums, nb);
    k_scan3<<<nb, 1024, 0, stream>>>(off, bsums, N, E);

    const int gmm = ((N + 63) / 64) * 2;    // 1564 blocks (row x col split)
    const int gag = (N + 15) / 16;          // 3125 agg blocks

    // layer 1 GEMM (register-prefetch pipeline) with distributed CSR fill
    k_mm1fill<<<gmm, 256, 0, stream>>>(X, W1h, W1l, dis, Hb, N, K1,
                                       src, dst, off, rank, csr16, E, gmm * 256);
    k_agg<<<gag, 256, 0, stream>>>(Hb, dis, off, csr16,
                                   (const float4*)b1, nullptr, X1h, X1l, N, 1);

    // layer 2
    k_mm2<<<gmm, 256, 0, stream>>>(X1h, X1l, W2h, W2l, dis, Hb, N, D_H);
    k_agg<<<gag, 256, 0, stream>>>(Hb, dis, off, csr16,
                                   (const float4*)b2, (float4*)out, nullptr, nullptr, N, 0);
}

// Round 12
// 261.764 us; speedup vs baseline: 1.1277x; 1.0295x over previous
//
#include <hip/hip_runtime.h>
#include <hip/hip_bf16.h>
#include <stdint.h>

#define D_H 128

typedef __bf16 bf16_t;
typedef unsigned short u16;
typedef bf16_t bf16x8 __attribute__((ext_vector_type(8)));
typedef bf16_t bf16x4 __attribute__((ext_vector_type(4)));
typedef float  f32x4  __attribute__((ext_vector_type(4)));

// ------- fused pre-pass: countrank + W prep + X hi/lo split ----------------
// blocks [0, gcr): rank[e] = atomicAdd(&cnt[dst[e]], 1)
// blocks [gcr, gcr+gw): transpose + hi/lo split of W1, W2
// blocks [gcr+gw, ...): split X (fp32) -> Xh, Xl (bf16), coalesced float4
__global__ void k_pre(const int* __restrict__ dst, int* __restrict__ cnt,
                      u16* __restrict__ rank, int E, int gcr, int gw,
                      const float* __restrict__ W1, bf16_t* __restrict__ W1h,
                      bf16_t* __restrict__ W1l, int K1,
                      const float* __restrict__ W2, bf16_t* __restrict__ W2h,
                      bf16_t* __restrict__ W2l, int K2,
                      const float* __restrict__ X, bf16_t* __restrict__ Xh,
                      bf16_t* __restrict__ Xl, int nx4) {
    int bx = (int)blockIdx.x;
    if (bx < gcr) {
        int e = bx * 256 + threadIdx.x;
        if (e < E) rank[e] = (u16)atomicAdd(&cnt[dst[e]], 1);
        return;
    }
    if (bx < gcr + gw) {
        int id = (bx - gcr) * 256 + threadIdx.x;
        int n1 = K1 * 128;
        if (id < n1) {
            int k = id >> 7, n = id & 127;
            float w = W1[id];
            bf16_t h = (bf16_t)w;
            W1h[(size_t)n * K1 + k] = h;
            W1l[(size_t)n * K1 + k] = (bf16_t)(w - (float)h);
        } else if (id < n1 + K2 * 128) {
            int id2 = id - n1;
            int k = id2 >> 7, n = id2 & 127;
            float w = W2[id2];
            bf16_t h = (bf16_t)w;
            W2h[(size_t)n * K2 + k] = h;
            W2l[(size_t)n * K2 + k] = (bf16_t)(w - (float)h);
        }
        return;
    }
    int id = (bx - gcr - gw) * 256 + threadIdx.x;   // id < nx4 = N*K1/4
    if (id < nx4) {
        float4 v = ((const float4*)X)[id];
        bf16_t h0 = (bf16_t)v.x, h1 = (bf16_t)v.y, h2 = (bf16_t)v.z, h3 = (bf16_t)v.w;
        ((bf16x4*)Xh)[id] = (bf16x4){h0, h1, h2, h3};
        ((bf16x4*)Xl)[id] = (bf16x4){(bf16_t)(v.x - (float)h0), (bf16_t)(v.y - (float)h1),
                                     (bf16_t)(v.z - (float)h2), (bf16_t)(v.w - (float)h3)};
    }
}

// ---------------- exclusive scan (3 kernels); scan1 also emits dis ----------
__global__ __launch_bounds__(1024) void k_scan1(const int* __restrict__ cnt,
                                                int* __restrict__ out,
                                                int* __restrict__ bsums,
                                                float* __restrict__ dis, int N) {
    __shared__ int tmp[1024];
    int t = threadIdx.x;
    int i = blockIdx.x * 1024 + t;
    int v = (i < N) ? cnt[i] : 0;
    if (i < N) dis[i] = 1.0f / sqrtf((float)(v + 1));
    tmp[t] = v;
    __syncthreads();
    for (int d = 1; d < 1024; d <<= 1) {
        int x = (t >= d) ? tmp[t - d] : 0;
        __syncthreads();
        tmp[t] += x;
        __syncthreads();
    }
    if (i < N) out[i] = tmp[t] - v;
    if (t == 1023) bsums[blockIdx.x] = tmp[t];
}

__global__ void k_scan2(int* __restrict__ bsums, int nb) {
    __shared__ int tmp[64];
    int t = threadIdx.x;
    int v = (t < nb) ? bsums[t] : 0;
    tmp[t] = v;
    __syncthreads();
    for (int d = 1; d < 64; d <<= 1) {
        int x = (t >= d) ? tmp[t - d] : 0;
        __syncthreads();
        tmp[t] += x;
        __syncthreads();
    }
    if (t < nb) bsums[t] = tmp[t] - v;
}

__global__ __launch_bounds__(1024) void k_scan3(int* __restrict__ off,
                                                const int* __restrict__ bsums,
                                                int N, int E) {
    int i = blockIdx.x * 1024 + threadIdx.x;
    if (i < N) off[i] += bsums[blockIdx.x];
    if (i == 0) off[N] = E;
}

// ---------------- unified MFMA GEMM (round-8 structure, bf16 hi/lo A) ------
// BM=64, BN=64, 256 thr = 4 waves, each wave 32x32 (2x2 MFMA tiles).
// blockIdx: row0=(bx>>1)*64, col0=(bx&1)*64. Distributed CSR fill (E=0 off).
#define LDK 40
#define FILL_PER 2
__global__ __launch_bounds__(256) void k_mm(
        const bf16_t* __restrict__ Ah, const bf16_t* __restrict__ Al,
        const bf16_t* __restrict__ Wh, const bf16_t* __restrict__ Wl,
        const float* __restrict__ dis, bf16_t* __restrict__ Cb,
        int N, int K,
        const int* __restrict__ src, const int* __restrict__ dst,
        const int* __restrict__ off, const u16* __restrict__ rank,
        u16* __restrict__ csr16, int E, int totThreads) {
    __shared__ bf16_t AsH[64][LDK];
    __shared__ bf16_t AsL[64][LDK];
    __shared__ bf16_t BsH[64][LDK];
    __shared__ bf16_t BsL[64][LDK];

    const int t    = threadIdx.x;
    const int lane = t & 63;
    const int wave = t >> 6;            // 0..3
    const int row0 = ((int)blockIdx.x >> 1) * 64;
    const int col0 = ((int)blockIdx.x & 1) * 64;
    const int wm   = (wave & 1) * 32;
    const int wn   = (wave >> 1) * 32;
    const int fm   = lane & 15;
    const int fq   = lane >> 4;

    // ---- fill prologue (layer 1 only; E=0 disables) ----
    const int g = (int)blockIdx.x * 256 + t;
    int epos[FILL_PER];
    u16 esrc[FILL_PER];
#pragma unroll
    for (int i = 0; i < FILL_PER; i++) {
        int e = g + i * totThreads;
        if (e < E) {
            int d = dst[e];
            epos[i] = off[d] + (int)rank[e];
            esrc[i] = (u16)src[e];
        } else {
            epos[i] = -1;
            esrc[i] = 0;
        }
    }

    const int r8 = t >> 2;              // 0..63
    const int c8 = t & 3;               // 0..3 (x8 bf16 = 32 k)
    const int gr = row0 + r8;

    f32x4 acc[2][2] = {};

    for (int k0 = 0; k0 < K; k0 += 32) {
        __syncthreads();
        {
            bf16x8 vh = {}, vl = {};
            if (gr < N) {
                vh = *(const bf16x8*)(Ah + (size_t)gr * K + k0 + c8 * 8);
                vl = *(const bf16x8*)(Al + (size_t)gr * K + k0 + c8 * 8);
            }
            *(bf16x8*)&AsH[r8][c8 * 8] = vh;
            *(bf16x8*)&AsL[r8][c8 * 8] = vl;
            *(bf16x8*)&BsH[r8][c8 * 8] = *(const bf16x8*)(Wh + (size_t)(col0 + r8) * K + k0 + c8 * 8);
            *(bf16x8*)&BsL[r8][c8 * 8] = *(const bf16x8*)(Wl + (size_t)(col0 + r8) * K + k0 + c8 * 8);
        }
        __syncthreads();

        bf16x8 ah[2], al[2], bh[2], bl[2];
#pragma unroll
        for (int i = 0; i < 2; i++) {
            ah[i] = *(const bf16x8*)&AsH[wm + i * 16 + fm][fq * 8];
            al[i] = *(const bf16x8*)&AsL[wm + i * 16 + fm][fq * 8];
            bh[i] = *(const bf16x8*)&BsH[wn + i * 16 + fm][fq * 8];
            bl[i] = *(const bf16x8*)&BsL[wn + i * 16 + fm][fq * 8];
        }
#pragma unroll
        for (int mi = 0; mi < 2; mi++)
#pragma unroll
            for (int ni = 0; ni < 2; ni++) {
                acc[mi][ni] = __builtin_amdgcn_mfma_f32_16x16x32_bf16(ah[mi], bh[ni], acc[mi][ni], 0, 0, 0);
                acc[mi][ni] = __builtin_amdgcn_mfma_f32_16x16x32_bf16(ah[mi], bl[ni], acc[mi][ni], 0, 0, 0);
                acc[mi][ni] = __builtin_amdgcn_mfma_f32_16x16x32_bf16(al[mi], bh[ni], acc[mi][ni], 0, 0, 0);
            }
    }

    // epilogue: C/D layout col=fm, row=fq*4+reg; scale by dis[row], store bf16
#pragma unroll
    for (int mi = 0; mi < 2; mi++)
#pragma unroll
        for (int r = 0; r < 4; r++) {
            int grow = row0 + wm + mi * 16 + fq * 4 + r;
            if (grow < N) {
                float dr = dis[grow];
#pragma unroll
                for (int ni = 0; ni < 2; ni++)
                    Cb[(size_t)grow * D_H + col0 + wn + ni * 16 + fm] = (bf16_t)(dr * acc[mi][ni][r]);
            }
        }

    // ---- fill epilogue: scattered 2B stores, fire and forget ----
#pragma unroll
    for (int i = 0; i < FILL_PER; i++)
        if (epos[i] >= 0) csr16[epos[i]] = esrc[i];
}

// ---------------- aggregation (16 lanes/node x bf16x8 = 16B/lane) ----------
// 16 nodes per 256-block (4 nodes/wave), edge loop unrolled x4
// -> 16 independent 256B row gathers in flight per wave, 2 requests/row.
__global__ __launch_bounds__(256) void k_agg(const bf16_t* __restrict__ Hb,
                                             const float* __restrict__ dis,
                                             const int* __restrict__ off,
                                             const u16* __restrict__ csr16,
                                             const float4* __restrict__ bias4,
                                             float4* __restrict__ outF,
                                             bf16_t* __restrict__ outH,
                                             bf16_t* __restrict__ outL,
                                             int N, int mode) {
    const int slot = threadIdx.x >> 4;           // 0..15: node slot
    const int lane = threadIdx.x & 15;           // feature group (8 bf16 = 16B)
    const int node = blockIdx.x * 16 + slot;
    if (node >= N) return;

    const bf16_t* Hrow = Hb + (size_t)lane * 8;

    float a0[8], a1[8], a2[8], a3[8];
    {
        bf16x8 v = *(const bf16x8*)(Hrow + (size_t)node * D_H);
#pragma unroll
        for (int j = 0; j < 8; j++) { a0[j] = (float)v[j]; a1[j] = 0.f; a2[j] = 0.f; a3[j] = 0.f; }
    }

    int p  = off[node];
    int p1 = off[node + 1];

    for (; p + 4 <= p1; p += 4) {
        int s0 = (int)csr16[p + 0], s1 = (int)csr16[p + 1];
        int s2 = (int)csr16[p + 2], s3 = (int)csr16[p + 3];
        bf16x8 h0 = *(const bf16x8*)(Hrow + (size_t)s0 * D_H);
        bf16x8 h1 = *(const bf16x8*)(Hrow + (size_t)s1 * D_H);
        bf16x8 h2 = *(const bf16x8*)(Hrow + (size_t)s2 * D_H);
        bf16x8 h3 = *(const bf16x8*)(Hrow + (size_t)s3 * D_H);
#pragma unroll
        for (int j = 0; j < 8; j++) {
            a0[j] += (float)h0[j];
            a1[j] += (float)h1[j];
            a2[j] += (float)h2[j];
            a3[j] += (float)h3[j];
        }
    }
    if (p + 2 <= p1) {
        int s0 = (int)csr16[p + 0], s1 = (int)csr16[p + 1];
        bf16x8 h0 = *(const bf16x8*)(Hrow + (size_t)s0 * D_H);
        bf16x8 h1 = *(const bf16x8*)(Hrow + (size_t)s1 * D_H);
#pragma unroll
        for (int j = 0; j < 8; j++) { a0[j] += (float)h0[j]; a1[j] += (float)h1[j]; }
        p += 2;
    }
    if (p < p1) {
        int s0 = (int)csr16[p];
        bf16x8 h0 = *(const bf16x8*)(Hrow + (size_t)s0 * D_H);
#pragma unroll
        for (int j = 0; j < 8; j++) a2[j] += (float)h0[j];
    }

    float sum[8];
#pragma unroll
    for (int j = 0; j < 8; j++) sum[j] = (a0[j] + a1[j]) + (a2[j] + a3[j]);

    const float  di = dis[node];
    const float4 b0 = bias4[lane * 2];
    const float4 b1 = bias4[lane * 2 + 1];
    float v0 = fmaf(di, sum[0], b0.x), v1 = fmaf(di, sum[1], b0.y);
    float v2 = fmaf(di, sum[2], b0.z), v3 = fmaf(di, sum[3], b0.w);
    float v4 = fmaf(di, sum[4], b1.x), v5 = fmaf(di, sum[5], b1.y);
    float v6 = fmaf(di, sum[6], b1.z), v7 = fmaf(di, sum[7], b1.w);

    if (mode == 1) {
        v0 = fmaxf(v0, 0.f); v1 = fmaxf(v1, 0.f); v2 = fmaxf(v2, 0.f); v3 = fmaxf(v3, 0.f);
        v4 = fmaxf(v4, 0.f); v5 = fmaxf(v5, 0.f); v6 = fmaxf(v6, 0.f); v7 = fmaxf(v7, 0.f);
        bf16_t h0 = (bf16_t)v0, h1 = (bf16_t)v1, h2 = (bf16_t)v2, h3 = (bf16_t)v3;
        bf16_t h4 = (bf16_t)v4, h5 = (bf16_t)v5, h6 = (bf16_t)v6, h7 = (bf16_t)v7;
        *(bf16x8*)(outH + (size_t)node * D_H + lane * 8) =
            (bf16x8){h0, h1, h2, h3, h4, h5, h6, h7};
        *(bf16x8*)(outL + (size_t)node * D_H + lane * 8) =
            (bf16x8){(bf16_t)(v0 - (float)h0), (bf16_t)(v1 - (float)h1),
                     (bf16_t)(v2 - (float)h2), (bf16_t)(v3 - (float)h3),
                     (bf16_t)(v4 - (float)h4), (bf16_t)(v5 - (float)h5),
                     (bf16_t)(v6 - (float)h6), (bf16_t)(v7 - (float)h7)};
    } else {
        outF[(size_t)node * 32 + lane * 2]     = make_float4(v0, v1, v2, v3);
        outF[(size_t)node * 32 + lane * 2 + 1] = make_float4(v4, v5, v6, v7);
    }
}

extern "C" void kernel_launch(void* const* d_in, const int* in_sizes, int n_in,
                              void* d_out, int out_size, void* d_ws, size_t ws_size,
                              hipStream_t stream) {
    const float* X  = (const float*)d_in[0];
    const int*   ei = (const int*)d_in[1];
    const float* W1 = (const float*)d_in[2];
    const float* b1 = (const float*)d_in[3];
    const float* W2 = (const float*)d_in[4];
    const float* b2 = (const float*)d_in[5];
    float* out = (float*)d_out;

    const int N  = in_sizes[0] / 256;   // 50000
    const int E  = in_sizes[1] / 2;     // 800000
    const int K1 = 256;

    const int* src = ei;
    const int* dst = ei + E;

    uintptr_t p = (uintptr_t)d_ws;
    auto carve = [&](size_t bytes) {
        uintptr_t q = p;
        p += (bytes + 255) & ~(size_t)255;
        return q;
    };
    int*    cnt   = (int*)carve((size_t)N * 4);
    int*    off   = (int*)carve((size_t)(N + 1) * 4);
    int*    bsums = (int*)carve(64 * 4);
    float*  dis   = (float*)carve((size_t)N * 4);
    u16*    rank  = (u16*)carve((size_t)E * 2);
    u16*    csr16 = (u16*)carve((size_t)E * 2);
    bf16_t* Hb    = (bf16_t*)carve((size_t)N * D_H * 2);
    bf16_t* X1h   = (bf16_t*)carve((size_t)N * D_H * 2);
    bf16_t* X1l   = (bf16_t*)carve((size_t)N * D_H * 2);
    bf16_t* Xh    = (bf16_t*)carve((size_t)N * K1 * 2);
    bf16_t* Xl    = (bf16_t*)carve((size_t)N * K1 * 2);
    bf16_t* W1h   = (bf16_t*)carve((size_t)K1 * D_H * 2);
    bf16_t* W1l   = (bf16_t*)carve((size_t)K1 * D_H * 2);
    bf16_t* W2h   = (bf16_t*)carve((size_t)D_H * D_H * 2);
    bf16_t* W2l   = (bf16_t*)carve((size_t)D_H * D_H * 2);

    const int nb = (N + 1023) / 1024;

    // fused pre-pass: countrank + W prep + X hi/lo split
    hipMemsetAsync(cnt, 0, (size_t)N * 4, stream);
    const int gcr = (E + 255) / 256;
    const int gw  = (K1 * 128 + D_H * 128 + 255) / 256;
    const int nx4 = N * K1 / 4;
    const int gx  = (nx4 + 255) / 256;
    k_pre<<<gcr + gw + gx, 256, 0, stream>>>(dst, cnt, rank, E, gcr, gw,
                                             W1, W1h, W1l, K1,
                                             W2, W2h, W2l, D_H,
                                             X, Xh, Xl, nx4);
    k_scan1<<<nb, 1024, 0, stream>>>(cnt, off, bsums, dis, N);
    k_scan2<<<1, 64, 0, stream>>>(bsums, nb);
    k_scan3<<<nb, 1024, 0, stream>>>(off, bsums, N, E);

    const int gmm = ((N + 63) / 64) * 2;    // 1564 blocks (row x col split)
    const int gag = (N + 15) / 16;          // 3125 agg blocks

    // layer 1: Hb = bf16(dis .* (X @ W1)) with distributed CSR fill
    k_mm<<<gmm, 256, 0, stream>>>(Xh, Xl, W1h, W1l, dis, Hb, N, K1,
                                  src, dst, off, rank, csr16, E, gmm * 256);
    k_agg<<<gag, 256, 0, stream>>>(Hb, dis, off, csr16,
                                   (const float4*)b1, nullptr, X1h, X1l, N, 1);

    // layer 2 (fill disabled via E=0)
    k_mm<<<gmm, 256, 0, stream>>>(X1h, X1l, W2h, W2l, dis, Hb, N, D_H,
                                  src, dst, off, rank, csr16, 0, gmm * 256);
    k_agg<<<gag, 256, 0, stream>>>(Hb, dis, off, csr16,
                                   (const float4*)b2, (float4*)out, nullptr, nullptr, N, 0);
}

// Round 13
// 250.077 us; speedup vs baseline: 1.1804x; 1.0467x over previous
//
#include <hip/hip_runtime.h>
#include <hip/hip_bf16.h>
#include <stdint.h>

#define D_H 128

typedef __bf16 bf16_t;
typedef unsigned short u16;
typedef bf16_t bf16x8 __attribute__((ext_vector_type(8)));
typedef bf16_t bf16x4 __attribute__((ext_vector_type(4)));
typedef float  f32x4  __attribute__((ext_vector_type(4)));

// ------- fused pre-pass: 4-way privatized countrank + W prep ---------------
// blocks [0, gcr): copy=bx&3; rank[e] = atomicAdd(&cnt4[copy*N + dst[e]], 1)
//                  (4x less per-line atomic serialization than single cnt)
// blocks [gcr, ..): transpose + hi/lo split of W1, W2
__global__ void k_pre(const int* __restrict__ dst, int* __restrict__ cnt4,
                      u16* __restrict__ rank, int E, int Nn, int gcr,
                      const float* __restrict__ W1, bf16_t* __restrict__ W1h,
                      bf16_t* __restrict__ W1l, int K1,
                      const float* __restrict__ W2, bf16_t* __restrict__ W2h,
                      bf16_t* __restrict__ W2l, int K2) {
    int bx = (int)blockIdx.x;
    if (bx < gcr) {
        int e = bx * 256 + threadIdx.x;
        if (e < E) {
            int d = dst[e];
            rank[e] = (u16)atomicAdd(&cnt4[(bx & 3) * Nn + d], 1);
        }
        return;
    }
    int id = (bx - gcr) * 256 + threadIdx.x;
    int n1 = K1 * 128;
    if (id < n1) {
        int k = id >> 7, n = id & 127;
        float w = W1[id];
        bf16_t h = (bf16_t)w;
        W1h[(size_t)n * K1 + k] = h;
        W1l[(size_t)n * K1 + k] = (bf16_t)(w - (float)h);
    } else if (id < n1 + K2 * 128) {
        int id2 = id - n1;
        int k = id2 >> 7, n = id2 & 127;
        float w = W2[id2];
        bf16_t h = (bf16_t)w;
        W2h[(size_t)n * K2 + k] = h;
        W2l[(size_t)n * K2 + k] = (bf16_t)(w - (float)h);
    }
}

// ---------------- exclusive scan; scan1 sums the 4 copies + emits dis ------
__global__ __launch_bounds__(1024) void k_scan1(const int* __restrict__ cnt4,
                                                int* __restrict__ out,
                                                int* __restrict__ bsums,
                                                float* __restrict__ dis, int N) {
    __shared__ int tmp[1024];
    int t = threadIdx.x;
    int i = blockIdx.x * 1024 + t;
    int v = 0;
    if (i < N) {
        v = cnt4[i] + cnt4[N + i] + cnt4[2 * N + i] + cnt4[3 * N + i];
        dis[i] = 1.0f / sqrtf((float)(v + 1));
    }
    tmp[t] = v;
    __syncthreads();
    for (int d = 1; d < 1024; d <<= 1) {
        int x = (t >= d) ? tmp[t - d] : 0;
        __syncthreads();
        tmp[t] += x;
        __syncthreads();
    }
    if (i < N) out[i] = tmp[t] - v;
    if (t == 1023) bsums[blockIdx.x] = tmp[t];
}

__global__ void k_scan2(int* __restrict__ bsums, int nb) {
    __shared__ int tmp[64];
    int t = threadIdx.x;
    int v = (t < nb) ? bsums[t] : 0;
    tmp[t] = v;
    __syncthreads();
    for (int d = 1; d < 64; d <<= 1) {
        int x = (t >= d) ? tmp[t - d] : 0;
        __syncthreads();
        tmp[t] += x;
        __syncthreads();
    }
    if (t < nb) bsums[t] = tmp[t] - v;
}

// scan3: finalize off, and emit per-copy bases offc[c][i] = off[i]+prefix(c)
__global__ __launch_bounds__(1024) void k_scan3(int* __restrict__ off,
                                                const int* __restrict__ bsums,
                                                const int* __restrict__ cnt4,
                                                int* __restrict__ offc,
                                                int N, int E) {
    int i = blockIdx.x * 1024 + threadIdx.x;
    if (i < N) {
        int o = off[i] + bsums[blockIdx.x];
        off[i] = o;
        int c0 = cnt4[i], c1 = cnt4[N + i], c2 = cnt4[2 * N + i];
        offc[i]         = o;
        offc[N + i]     = o + c0;
        offc[2 * N + i] = o + c0 + c1;
        offc[3 * N + i] = o + c0 + c1 + c2;
    }
    if (i == 0) off[N] = E;
}

// ---------------- MFMA GEMM tiles: BM=64, BN=64, 256 thr = 4 waves --------
// Round-8 structure (best measured). blockIdx: row0=(bx>>1)*64, col0=(bx&1)*64.
#define LDK 40
#define FILL_PER 2

// layer-1 (fp32 A, hi/lo split in-kernel) + distributed atomic-free CSR fill
__global__ __launch_bounds__(256) void k_mm1fill(
        const float* __restrict__ Af,
        const bf16_t* __restrict__ Wh, const bf16_t* __restrict__ Wl,
        const float* __restrict__ dis, bf16_t* __restrict__ Cb,
        int N, int K,
        const int* __restrict__ src, const int* __restrict__ dst,
        const int* __restrict__ offc, const u16* __restrict__ rank,
        u16* __restrict__ csr16, int E, int totThreads) {
    __shared__ bf16_t AsH[64][LDK];
    __shared__ bf16_t AsL[64][LDK];
    __shared__ bf16_t BsH[64][LDK];
    __shared__ bf16_t BsL[64][LDK];

    const int t    = threadIdx.x;
    const int lane = t & 63;
    const int wave = t >> 6;            // 0..3
    const int row0 = ((int)blockIdx.x >> 1) * 64;
    const int col0 = ((int)blockIdx.x & 1) * 64;
    const int wm   = (wave & 1) * 32;
    const int wn   = (wave >> 1) * 32;
    const int fm   = lane & 15;
    const int fq   = lane >> 4;

    // ---- fill prologue: resolve scatter addresses (copy from count layout) --
    const int g = (int)blockIdx.x * 256 + t;
    int epos[FILL_PER];
    u16 esrc[FILL_PER];
#pragma unroll
    for (int i = 0; i < FILL_PER; i++) {
        int e = g + i * totThreads;
        if (e < E) {
            int d    = dst[e];
            int copy = (e >> 8) & 3;    // matches k_pre: copy = block&3, 256/block
            epos[i] = offc[copy * N + d] + (int)rank[e];
            esrc[i] = (u16)src[e];
        } else {
            epos[i] = -1;
            esrc[i] = 0;
        }
    }

    f32x4 acc[2][2] = {};

    for (int k0 = 0; k0 < K; k0 += 32) {
        __syncthreads();
        // stage A: 64 rows x 32 k fp32 = 512 float4; 2/thread, split hi/lo
#pragma unroll
        for (int i = 0; i < 2; i++) {
            int idx = t + i * 256;
            int r   = idx >> 3;
            int c4  = idx & 7;
            int gr  = row0 + r;
            float4 v = make_float4(0.f, 0.f, 0.f, 0.f);
            if (gr < N) v = *(const float4*)(Af + (size_t)gr * K + k0 + c4 * 4);
            bf16_t h0 = (bf16_t)v.x, h1 = (bf16_t)v.y, h2 = (bf16_t)v.z, h3 = (bf16_t)v.w;
            bf16_t l0 = (bf16_t)(v.x - (float)h0);
            bf16_t l1 = (bf16_t)(v.y - (float)h1);
            bf16_t l2 = (bf16_t)(v.z - (float)h2);
            bf16_t l3 = (bf16_t)(v.w - (float)h3);
            *(bf16x4*)&AsH[r][c4 * 4] = (bf16x4){h0, h1, h2, h3};
            *(bf16x4*)&AsL[r][c4 * 4] = (bf16x4){l0, l1, l2, l3};
        }
        // stage B: 64 cols x 32 k; 1/thread per plane
        {
            int r  = t >> 2;
            int c8 = t & 3;
            *(bf16x8*)&BsH[r][c8 * 8] = *(const bf16x8*)(Wh + (size_t)(col0 + r) * K + k0 + c8 * 8);
            *(bf16x8*)&BsL[r][c8 * 8] = *(const bf16x8*)(Wl + (size_t)(col0 + r) * K + k0 + c8 * 8);
        }
        __syncthreads();

        bf16x8 ah[2], al[2], bh[2], bl[2];
#pragma unroll
        for (int i = 0; i < 2; i++) {
            ah[i] = *(const bf16x8*)&AsH[wm + i * 16 + fm][fq * 8];
            al[i] = *(const bf16x8*)&AsL[wm + i * 16 + fm][fq * 8];
            bh[i] = *(const bf16x8*)&BsH[wn + i * 16 + fm][fq * 8];
            bl[i] = *(const bf16x8*)&BsL[wn + i * 16 + fm][fq * 8];
        }
#pragma unroll
        for (int mi = 0; mi < 2; mi++)
#pragma unroll
            for (int ni = 0; ni < 2; ni++) {
                acc[mi][ni] = __builtin_amdgcn_mfma_f32_16x16x32_bf16(ah[mi], bh[ni], acc[mi][ni], 0, 0, 0);
                acc[mi][ni] = __builtin_amdgcn_mfma_f32_16x16x32_bf16(ah[mi], bl[ni], acc[mi][ni], 0, 0, 0);
                acc[mi][ni] = __builtin_amdgcn_mfma_f32_16x16x32_bf16(al[mi], bh[ni], acc[mi][ni], 0, 0, 0);
            }
    }

#pragma unroll
    for (int mi = 0; mi < 2; mi++)
#pragma unroll
        for (int r = 0; r < 4; r++) {
            int grow = row0 + wm + mi * 16 + fq * 4 + r;
            if (grow < N) {
                float dr = dis[grow];
#pragma unroll
                for (int ni = 0; ni < 2; ni++)
                    Cb[(size_t)grow * D_H + col0 + wn + ni * 16 + fm] = (bf16_t)(dr * acc[mi][ni][r]);
            }
        }

    // ---- fill epilogue: scattered 2B stores, fire and forget ----
#pragma unroll
    for (int i = 0; i < FILL_PER; i++)
        if (epos[i] >= 0) csr16[epos[i]] = esrc[i];
}

// layer-2 (bf16 hi/lo A), round-8 structure
__global__ __launch_bounds__(256) void k_mm2(const bf16_t* __restrict__ Ah,
                                             const bf16_t* __restrict__ Al,
                                             const bf16_t* __restrict__ Wh,
                                             const bf16_t* __restrict__ Wl,
                                             const float* __restrict__ dis,
                                             bf16_t* __restrict__ Cb,
                                             int N, int K) {
    __shared__ bf16_t AsH[64][LDK];
    __shared__ bf16_t AsL[64][LDK];
    __shared__ bf16_t BsH[64][LDK];
    __shared__ bf16_t BsL[64][LDK];

    const int t    = threadIdx.x;
    const int lane = t & 63;
    const int wave = t >> 6;
    const int row0 = ((int)blockIdx.x >> 1) * 64;
    const int col0 = ((int)blockIdx.x & 1) * 64;
    const int wm   = (wave & 1) * 32;
    const int wn   = (wave >> 1) * 32;
    const int fm   = lane & 15;
    const int fq   = lane >> 4;

    f32x4 acc[2][2] = {};

    for (int k0 = 0; k0 < K; k0 += 32) {
        __syncthreads();
        {
            int r  = t >> 2;
            int c8 = t & 3;
            int gr = row0 + r;
            bf16x8 vh = {}, vl = {};
            if (gr < N) {
                vh = *(const bf16x8*)(Ah + (size_t)gr * K + k0 + c8 * 8);
                vl = *(const bf16x8*)(Al + (size_t)gr * K + k0 + c8 * 8);
            }
            *(bf16x8*)&AsH[r][c8 * 8] = vh;
            *(bf16x8*)&AsL[r][c8 * 8] = vl;
            *(bf16x8*)&BsH[r][c8 * 8] = *(const bf16x8*)(Wh + (size_t)(col0 + r) * K + k0 + c8 * 8);
            *(bf16x8*)&BsL[r][c8 * 8] = *(const bf16x8*)(Wl + (size_t)(col0 + r) * K + k0 + c8 * 8);
        }
        __syncthreads();

        bf16x8 ah[2], al[2], bh[2], bl[2];
#pragma unroll
        for (int i = 0; i < 2; i++) {
            ah[i] = *(const bf16x8*)&AsH[wm + i * 16 + fm][fq * 8];
            al[i] = *(const bf16x8*)&AsL[wm + i * 16 + fm][fq * 8];
            bh[i] = *(const bf16x8*)&BsH[wn + i * 16 + fm][fq * 8];
            bl[i] = *(const bf16x8*)&BsL[wn + i * 16 + fm][fq * 8];
        }
#pragma unroll
        for (int mi = 0; mi < 2; mi++)
#pragma unroll
            for (int ni = 0; ni < 2; ni++) {
                acc[mi][ni] = __builtin_amdgcn_mfma_f32_16x16x32_bf16(ah[mi], bh[ni], acc[mi][ni], 0, 0, 0);
                acc[mi][ni] = __builtin_amdgcn_mfma_f32_16x16x32_bf16(ah[mi], bl[ni], acc[mi][ni], 0, 0, 0);
                acc[mi][ni] = __builtin_amdgcn_mfma_f32_16x16x32_bf16(al[mi], bh[ni], acc[mi][ni], 0, 0, 0);
            }
    }

#pragma unroll
    for (int mi = 0; mi < 2; mi++)
#pragma unroll
        for (int r = 0; r < 4; r++) {
            int grow = row0 + wm + mi * 16 + fq * 4 + r;
            if (grow < N) {
                float dr = dis[grow];
#pragma unroll
                for (int ni = 0; ni < 2; ni++)
                    Cb[(size_t)grow * D_H + col0 + wn + ni * 16 + fm] = (bf16_t)(dr * acc[mi][ni][r]);
            }
        }
}

// ---------------- aggregation (16 lanes/node x bf16x8 = 16B/lane) ----------
__global__ __launch_bounds__(256) void k_agg(const bf16_t* __restrict__ Hb,
                                             const float* __restrict__ dis,
                                             const int* __restrict__ off,
                                             const u16* __restrict__ csr16,
                                             const float4* __restrict__ bias4,
                                             float4* __restrict__ outF,
                                             bf16_t* __restrict__ outH,
                                             bf16_t* __restrict__ outL,
                                             int N, int mode) {
    const int slot = threadIdx.x >> 4;           // 0..15: node slot
    const int lane = threadIdx.x & 15;           // feature group (8 bf16 = 16B)
    const int node = blockIdx.x * 16 + slot;
    if (node >= N) return;

    const bf16_t* Hrow = Hb + (size_t)lane * 8;

    float a0[8], a1[8], a2[8], a3[8];
    {
        bf16x8 v = *(const bf16x8*)(Hrow + (size_t)node * D_H);
#pragma unroll
        for (int j = 0; j < 8; j++) { a0[j] = (float)v[j]; a1[j] = 0.f; a2[j] = 0.f; a3[j] = 0.f; }
    }

    int p  = off[node];
    int p1 = off[node + 1];

    for (; p + 4 <= p1; p += 4) {
        int s0 = (int)csr16[p + 0], s1 = (int)csr16[p + 1];
        int s2 = (int)csr16[p + 2], s3 = (int)csr16[p + 3];
        bf16x8 h0 = *(const bf16x8*)(Hrow + (size_t)s0 * D_H);
        bf16x8 h1 = *(const bf16x8*)(Hrow + (size_t)s1 * D_H);
        bf16x8 h2 = *(const bf16x8*)(Hrow + (size_t)s2 * D_H);
        bf16x8 h3 = *(const bf16x8*)(Hrow + (size_t)s3 * D_H);
#pragma unroll
        for (int j = 0; j < 8; j++) {
            a0[j] += (float)h0[j];
            a1[j] += (float)h1[j];
            a2[j] += (float)h2[j];
            a3[j] += (float)h3[j];
        }
    }
    if (p + 2 <= p1) {
        int s0 = (int)csr16[p + 0], s1 = (int)csr16[p + 1];
        bf16x8 h0 = *(const bf16x8*)(Hrow + (size_t)s0 * D_H);
        bf16x8 h1 = *(const bf16x8*)(Hrow + (size_t)s1 * D_H);
#pragma unroll
        for (int j = 0; j < 8; j++) { a0[j] += (float)h0[j]; a1[j] += (float)h1[j]; }
        p += 2;
    }
    if (p < p1) {
        int s0 = (int)csr16[p];
        bf16x8 h0 = *(const bf16x8*)(Hrow + (size_t)s0 * D_H);
#pragma unroll
        for (int j = 0; j < 8; j++) a2[j] += (float)h0[j];
    }

    float sum[8];
#pragma unroll
    for (int j = 0; j < 8; j++) sum[j] = (a0[j] + a1[j]) + (a2[j] + a3[j]);

    const float  di = dis[node];
    const float4 b0 = bias4[lane * 2];
    const float4 b1 = bias4[lane * 2 + 1];
    float v0 = fmaf(di, sum[0], b0.x), v1 = fmaf(di, sum[1], b0.y);
    float v2 = fmaf(di, sum[2], b0.z), v3 = fmaf(di, sum[3], b0.w);
    float v4 = fmaf(di, sum[4], b1.x), v5 = fmaf(di, sum[5], b1.y);
    float v6 = fmaf(di, sum[6], b1.z), v7 = fmaf(di, sum[7], b1.w);

    if (mode == 1) {
        v0 = fmaxf(v0, 0.f); v1 = fmaxf(v1, 0.f); v2 = fmaxf(v2, 0.f); v3 = fmaxf(v3, 0.f);
        v4 = fmaxf(v4, 0.f); v5 = fmaxf(v5, 0.f); v6 = fmaxf(v6, 0.f); v7 = fmaxf(v7, 0.f);
        bf16_t h0 = (bf16_t)v0, h1 = (bf16_t)v1, h2 = (bf16_t)v2, h3 = (bf16_t)v3;
        bf16_t h4 = (bf16_t)v4, h5 = (bf16_t)v5, h6 = (bf16_t)v6, h7 = (bf16_t)v7;
        *(bf16x8*)(outH + (size_t)node * D_H + lane * 8) =
            (bf16x8){h0, h1, h2, h3, h4, h5, h6, h7};
        *(bf16x8*)(outL + (size_t)node * D_H + lane * 8) =
            (bf16x8){(bf16_t)(v0 - (float)h0), (bf16_t)(v1 - (float)h1),
                     (bf16_t)(v2 - (float)h2), (bf16_t)(v3 - (float)h3),
                     (bf16_t)(v4 - (float)h4), (bf16_t)(v5 - (float)h5),
                     (bf16_t)(v6 - (float)h6), (bf16_t)(v7 - (float)h7)};
    } else {
        outF[(size_t)node * 32 + lane * 2]     = make_float4(v0, v1, v2, v3);
        outF[(size_t)node * 32 + lane * 2 + 1] = make_float4(v4, v5, v6, v7);
    }
}

extern "C" void kernel_launch(void* const* d_in, const int* in_sizes, int n_in,
                              void* d_out, int out_size, void* d_ws, size_t ws_size,
                              hipStream_t stream) {
    const float* X  = (const float*)d_in[0];
    const int*   ei = (const int*)d_in[1];
    const float* W1 = (const float*)d_in[2];
    const float* b1 = (const float*)d_in[3];
    const float* W2 = (const float*)d_in[4];
    const float* b2 = (const float*)d_in[5];
    float* out = (float*)d_out;

    const int N  = in_sizes[0] / 256;   // 50000
    const int E  = in_sizes[1] / 2;     // 800000
    const int K1 = 256;

    const int* src = ei;
    const int* dst = ei + E;

    uintptr_t p = (uintptr_t)d_ws;
    auto carve = [&](size_t bytes) {
        uintptr_t q = p;
        p += (bytes + 255) & ~(size_t)255;
        return q;
    };
    int*    cnt4  = (int*)carve((size_t)N * 4 * 4);     // 4 privatized copies
    int*    off   = (int*)carve((size_t)(N + 1) * 4);
    int*    offc  = (int*)carve((size_t)N * 4 * 4);     // per-copy bases
    int*    bsums = (int*)carve(64 * 4);
    float*  dis   = (float*)carve((size_t)N * 4);
    u16*    rank  = (u16*)carve((size_t)E * 2);
    u16*    csr16 = (u16*)carve((size_t)E * 2);
    bf16_t* Hb    = (bf16_t*)carve((size_t)N * D_H * 2);
    bf16_t* X1h   = (bf16_t*)carve((size_t)N * D_H * 2);
    bf16_t* X1l   = (bf16_t*)carve((size_t)N * D_H * 2);
    bf16_t* W1h   = (bf16_t*)carve((size_t)K1 * D_H * 2);
    bf16_t* W1l   = (bf16_t*)carve((size_t)K1 * D_H * 2);
    bf16_t* W2h   = (bf16_t*)carve((size_t)D_H * D_H * 2);
    bf16_t* W2l   = (bf16_t*)carve((size_t)D_H * D_H * 2);

    const int nb = (N + 1023) / 1024;

    // fused pre-pass: 4-way privatized countrank + weight prep
    hipMemsetAsync(cnt4, 0, (size_t)N * 4 * 4, stream);
    const int gcr = (E + 255) / 256;
    const int gw  = (K1 * 128 + D_H * 128 + 255) / 256;
    k_pre<<<gcr + gw, 256, 0, stream>>>(dst, cnt4, rank, E, N, gcr,
                                        W1, W1h, W1l, K1,
                                        W2, W2h, W2l, D_H);
    k_scan1<<<nb, 1024, 0, stream>>>(cnt4, off, bsums, dis, N);
    k_scan2<<<1, 64, 0, stream>>>(bsums, nb);
    k_scan3<<<nb, 1024, 0, stream>>>(off, bsums, cnt4, offc, N, E);

    const int gmm = ((N + 63) / 64) * 2;    // 1564 blocks (row x col split)
    const int gag = (N + 15) / 16;          // 3125 agg blocks

    // layer 1 GEMM (round-8 structure) with distributed atomic-free CSR fill
    k_mm1fill<<<gmm, 256, 0, stream>>>(X, W1h, W1l, dis, Hb, N, K1,
                                       src, dst, offc, rank, csr16, E, gmm * 256);
    k_agg<<<gag, 256, 0, stream>>>(Hb, dis, off, csr16,
                                   (const float4*)b1, nullptr, X1h, X1l, N, 1);

    // layer 2
    k_mm2<<<gmm, 256, 0, stream>>>(X1h, X1l, W2h, W2l, dis, Hb, N, D_H);
    k_agg<<<gag, 256, 0, stream>>>(Hb, dis, off, csr16,
                                   (const float4*)b2, (float4*)out, nullptr, nullptr, N, 0);
}